// Round 1
// baseline (3488.749 us; speedup 1.0000x reference)
//
#include <hip/hip_runtime.h>
#include <hip/hip_bf16.h>

#define NN 50000
#define EE 800000
#define DD 512
#define BB 64
#define LL 4
#define OUTC 2
#define EPSV 1e-5f

typedef __bf16 bf16x8 __attribute__((ext_vector_type(8)));
typedef float floatx4 __attribute__((ext_vector_type(4)));

__device__ __forceinline__ unsigned short f2bf(float x) {
    union { __hip_bfloat16 b; unsigned short u; } cv;
    cv.b = __float2bfloat16(x);
    return cv.u;
}
__device__ __forceinline__ float bf2f(unsigned short u) {
    union { __hip_bfloat16 b; unsigned short u; } cv;
    cv.u = u;
    return __bfloat162float(cv.b);
}

__device__ __forceinline__ floatx4 mfma16(bf16x8 a, bf16x8 b, floatx4 c) {
    return __builtin_amdgcn_mfma_f32_16x16x32_bf16(a, b, c, 0, 0, 0);
}

// ---------------- init scratch ----------------
__global__ void k_init(float* deg, int* cnt, int* fill, int* gstart, int* gend,
                       float* psum, unsigned int* pmax) {
    int i = blockIdx.x * blockDim.x + threadIdx.x;
    if (i < NN) { deg[i] = 1.0f; cnt[i] = 0; fill[i] = 0; }
    if (i < BB) { gstart[i] = NN; gend[i] = 0; }
    if (i < BB * DD) { psum[i] = 0.f; pmax[i] = 0u; }
}

// ---------------- weighted degree + in-degree counts ----------------
__global__ void k_deg(const int* __restrict__ ei, const int* __restrict__ sd,
                      float* __restrict__ deg, int* __restrict__ cnt) {
    int e = blockIdx.x * blockDim.x + threadIdx.x;
    if (e >= EE) return;
    int c = ei[EE + e];
    float w = (sd[e] == 1) ? 1.0f : 0.7f;
    atomicAdd(&deg[c], w);
    atomicAdd(&cnt[c], 1);
}

__global__ void k_dis(const float* __restrict__ deg, float* __restrict__ dis) {
    int i = blockIdx.x * blockDim.x + threadIdx.x;
    if (i < NN) dis[i] = rsqrtf(fmaxf(deg[i], EPSV));
}

// ---------------- exclusive scan of counts -> rowptr ----------------
__global__ void k_scan1(const int* __restrict__ cnt, int* __restrict__ rowptr,
                        int* __restrict__ bsum) {
    __shared__ int sh[256];
    const int t = threadIdx.x;
    const int i = blockIdx.x * 256 + t;
    int v = (i < NN) ? cnt[i] : 0;
    sh[t] = v;
    __syncthreads();
    for (int off = 1; off < 256; off <<= 1) {
        int y = (t >= off) ? sh[t - off] : 0;
        __syncthreads();
        if (t >= off) sh[t] += y;
        __syncthreads();
    }
    if (i < NN) rowptr[i] = sh[t] - v;   // exclusive
    if (t == 255) bsum[blockIdx.x] = sh[255];
}

__global__ void k_scan2(int* __restrict__ bsum, int* __restrict__ rowptr, int nb) {
    if (threadIdx.x == 0 && blockIdx.x == 0) {
        int run = 0;
        for (int b = 0; b < nb; b++) { int t = bsum[b]; bsum[b] = run; run += t; }
        rowptr[NN] = run;
    }
}

__global__ void k_scan3(int* __restrict__ rowptr, const int* __restrict__ bsum) {
    int i = blockIdx.x * blockDim.x + threadIdx.x;
    if (i < NN) rowptr[i] += bsum[i >> 8];
}

// ---------------- CSR fill: per-dest src list + edge norm ----------------
__global__ void k_fill(const int* __restrict__ ei, const int* __restrict__ sd,
                       const float* __restrict__ dis, const int* __restrict__ rowptr,
                       int* __restrict__ fill, int* __restrict__ srcs,
                       float* __restrict__ enorm) {
    int e = blockIdx.x * blockDim.x + threadIdx.x;
    if (e >= EE) return;
    int s = ei[e];
    int c = ei[EE + e];
    float w = (sd[e] == 1) ? 1.0f : 0.7f;
    int p = rowptr[c] + atomicAdd(&fill[c], 1);
    srcs[p] = s;
    enorm[p] = dis[s] * w * dis[c];
}

// ---------------- weights: fp32 -> transposed bf16 hi/lo ----------------
__global__ void k_wt(const float* __restrict__ Wc, unsigned short* __restrict__ WThi,
                     unsigned short* __restrict__ WTlo) {
    int i = blockIdx.x * blockDim.x + threadIdx.x;  // < LL*DD*DD
    int l = i >> 18;
    int rem = i & ((DD * DD) - 1);
    int n = rem >> 9;
    int k = rem & (DD - 1);
    float v = Wc[(l << 18) + (k << 9) + n];
    unsigned short hb = f2bf(v);
    WThi[i] = hb;
    WTlo[i] = f2bf(v - bf2f(hb));
}

// ---------------- fp32 -> bf16 hi/lo split (layer-0 input x) ----------------
__global__ void k_split(const float* __restrict__ src, unsigned short* __restrict__ hi,
                        unsigned short* __restrict__ lo, int n) {
    int i = blockIdx.x * blockDim.x + threadIdx.x;
    if (i >= n) return;
    float v = src[i];
    unsigned short hb = f2bf(v);
    hi[i] = hb;
    lo[i] = f2bf(v - bf2f(hb));
}

// ---------------- GEMM: C[N,D] = (Ahi+Alo) @ (Bhi+Blo), B given transposed [n][k] ----------------
__launch_bounds__(256)
__global__ void k_gemm(const unsigned short* __restrict__ Ahi,
                       const unsigned short* __restrict__ Alo,
                       const unsigned short* __restrict__ Bhi,
                       const unsigned short* __restrict__ Blo,
                       float* __restrict__ C) {
    const int wid = threadIdx.x >> 6;
    const int lane = threadIdx.x & 63;
    const int l15 = lane & 15;
    const int quad = lane >> 4;
    const int m0 = blockIdx.x * 64 + wid * 16;
    const int n0 = blockIdx.y * 64;
    int arow = m0 + l15;
    if (arow > NN - 1) arow = NN - 1;  // clamp for loads; stores guarded
    const unsigned short* pah = Ahi + (size_t)arow * DD + quad * 8;
    const unsigned short* pal = Alo + (size_t)arow * DD + quad * 8;
    const unsigned short* pbh = Bhi + (size_t)(n0 + l15) * DD + quad * 8;
    const unsigned short* pbl = Blo + (size_t)(n0 + l15) * DD + quad * 8;
    floatx4 acc0 = {0.f, 0.f, 0.f, 0.f};
    floatx4 acc1 = acc0, acc2 = acc0, acc3 = acc0;
    for (int k0 = 0; k0 < DD; k0 += 32) {
        bf16x8 ah = *(const bf16x8*)(pah + k0);
        bf16x8 al = *(const bf16x8*)(pal + k0);
        bf16x8 bh0 = *(const bf16x8*)(pbh + k0);
        bf16x8 bl0 = *(const bf16x8*)(pbl + k0);
        bf16x8 bh1 = *(const bf16x8*)(pbh + 16 * DD + k0);
        bf16x8 bl1 = *(const bf16x8*)(pbl + 16 * DD + k0);
        bf16x8 bh2 = *(const bf16x8*)(pbh + 32 * DD + k0);
        bf16x8 bl2 = *(const bf16x8*)(pbl + 32 * DD + k0);
        bf16x8 bh3 = *(const bf16x8*)(pbh + 48 * DD + k0);
        bf16x8 bl3 = *(const bf16x8*)(pbl + 48 * DD + k0);
        acc0 = mfma16(ah, bh0, acc0); acc0 = mfma16(ah, bl0, acc0); acc0 = mfma16(al, bh0, acc0);
        acc1 = mfma16(ah, bh1, acc1); acc1 = mfma16(ah, bl1, acc1); acc1 = mfma16(al, bh1, acc1);
        acc2 = mfma16(ah, bh2, acc2); acc2 = mfma16(ah, bl2, acc2); acc2 = mfma16(al, bh2, acc2);
        acc3 = mfma16(ah, bh3, acc3); acc3 = mfma16(ah, bl3, acc3); acc3 = mfma16(al, bh3, acc3);
    }
    const int rbase = m0 + quad * 4;
    floatx4 av[4] = {acc0, acc1, acc2, acc3};
#pragma unroll
    for (int nt = 0; nt < 4; nt++) {
        const int gcol = n0 + nt * 16 + l15;
#pragma unroll
        for (int r = 0; r < 4; r++) {
            const int grow = rbase + r;
            if (grow < NN) C[(size_t)grow * DD + gcol] = av[nt][r];
        }
    }
}

// ---------------- aggregate + bias + BN + ReLU + bf16 hi/lo split ----------------
__device__ __forceinline__ void bn_pack_store(
    float v0, float v1, float v2, float v3, int cidx,
    const float4* __restrict__ bc4, const float4* __restrict__ g4,
    const float4* __restrict__ b4, const float4* __restrict__ rm4,
    const float4* __restrict__ rv4, uint2* __restrict__ oh, uint2* __restrict__ ol) {
    float4 bcv = bc4[cidx], gv = g4[cidx], bv = b4[cidx], rmv = rm4[cidx], rvv = rv4[cidx];
    float h0 = fmaxf(gv.x * (v0 + bcv.x - rmv.x) * rsqrtf(rvv.x + EPSV) + bv.x, 0.f);
    float h1 = fmaxf(gv.y * (v1 + bcv.y - rmv.y) * rsqrtf(rvv.y + EPSV) + bv.y, 0.f);
    float h2 = fmaxf(gv.z * (v2 + bcv.z - rmv.z) * rsqrtf(rvv.z + EPSV) + bv.z, 0.f);
    float h3 = fmaxf(gv.w * (v3 + bcv.w - rmv.w) * rsqrtf(rvv.w + EPSV) + bv.w, 0.f);
    unsigned short p0 = f2bf(h0), p1 = f2bf(h1), p2 = f2bf(h2), p3 = f2bf(h3);
    uint2 uh;
    uh.x = (unsigned)p0 | ((unsigned)p1 << 16);
    uh.y = (unsigned)p2 | ((unsigned)p3 << 16);
    unsigned short q0 = f2bf(h0 - bf2f(p0)), q1 = f2bf(h1 - bf2f(p1));
    unsigned short q2 = f2bf(h2 - bf2f(p2)), q3 = f2bf(h3 - bf2f(p3));
    uint2 ul;
    ul.x = (unsigned)q0 | ((unsigned)q1 << 16);
    ul.y = (unsigned)q2 | ((unsigned)q3 << 16);
    oh[cidx] = uh;
    ol[cidx] = ul;
}

__launch_bounds__(64)
__global__ void k_agg(const float* __restrict__ hw, const int* __restrict__ rowptr,
                      const int* __restrict__ srcs, const float* __restrict__ enorm,
                      const float* __restrict__ dis,
                      const float* __restrict__ bcl, const float* __restrict__ gl,
                      const float* __restrict__ bl_, const float* __restrict__ rml,
                      const float* __restrict__ rvl,
                      unsigned short* __restrict__ Hhi, unsigned short* __restrict__ Hlo) {
    const int n = blockIdx.x;
    const int lane = threadIdx.x;
    const float4* rowp = (const float4*)(hw + (size_t)n * DD);
    const float dn = dis[n];
    const float sw = dn * dn;  // self-loop norm
    float4 a0 = rowp[lane];
    float4 a1 = rowp[lane + 64];
    float x0 = a0.x * sw, x1 = a0.y * sw, x2 = a0.z * sw, x3 = a0.w * sw;
    float y0 = a1.x * sw, y1 = a1.y * sw, y2 = a1.z * sw, y3 = a1.w * sw;
    const int s0 = rowptr[n], s1 = rowptr[n + 1];
    for (int i = s0; i < s1; i++) {
        const int s = srcs[i];
        const float wn = enorm[i];
        const float4* rp = (const float4*)(hw + (size_t)s * DD);
        float4 b0 = rp[lane];
        float4 b1 = rp[lane + 64];
        x0 = fmaf(b0.x, wn, x0); x1 = fmaf(b0.y, wn, x1);
        x2 = fmaf(b0.z, wn, x2); x3 = fmaf(b0.w, wn, x3);
        y0 = fmaf(b1.x, wn, y0); y1 = fmaf(b1.y, wn, y1);
        y2 = fmaf(b1.z, wn, y2); y3 = fmaf(b1.w, wn, y3);
    }
    const float4* bc4 = (const float4*)bcl;
    const float4* g4 = (const float4*)gl;
    const float4* b4 = (const float4*)bl_;
    const float4* rm4 = (const float4*)rml;
    const float4* rv4 = (const float4*)rvl;
    uint2* oh = (uint2*)(Hhi + (size_t)n * DD);
    uint2* ol = (uint2*)(Hlo + (size_t)n * DD);
    bn_pack_store(x0, x1, x2, x3, lane, bc4, g4, b4, rm4, rv4, oh, ol);
    bn_pack_store(y0, y1, y2, y3, lane + 64, bc4, g4, b4, rm4, rv4, oh, ol);
}

// ---------------- graph node ranges (batch is sorted) ----------------
__global__ void k_bounds(const int* __restrict__ batch, int* __restrict__ gstart,
                         int* __restrict__ gend) {
    int n = blockIdx.x * blockDim.x + threadIdx.x;
    if (n >= NN) return;
    int g = batch[n];
    atomicMin(&gstart[g], n);
    atomicMax(&gend[g], n + 1);
}

// ---------------- mean/max pooling (8 slices per graph) ----------------
__launch_bounds__(512)
__global__ void k_pool(const unsigned short* __restrict__ Hhi,
                       const unsigned short* __restrict__ Hlo,
                       const int* __restrict__ gstart, const int* __restrict__ gend,
                       float* __restrict__ psum, unsigned int* __restrict__ pmax) {
    const int g = blockIdx.x;
    const int sl = blockIdx.y;
    const int c = threadIdx.x;
    const int s0 = gstart[g], e0 = gend[g];
    if (e0 <= s0) return;
    const int len = e0 - s0;
    const int chunk = (len + 7) >> 3;
    const int lo = s0 + sl * chunk;
    const int hi = min(lo + chunk, e0);
    float sum = 0.f, mx = 0.f;
    for (int n = lo; n < hi; n++) {
        float v = bf2f(Hhi[(size_t)n * DD + c]) + bf2f(Hlo[(size_t)n * DD + c]);
        sum += v;
        mx = fmaxf(mx, v);
    }
    if (lo < hi) {
        atomicAdd(&psum[g * DD + c], sum);
        atomicMax(&pmax[g * DD + c], __float_as_uint(fmaxf(mx, 0.f)));  // h >= 0
    }
}

// ---------------- final linear + log_softmax ----------------
__global__ void k_final(const float* __restrict__ psum, const unsigned int* __restrict__ pmax,
                        const int* __restrict__ gstart, const int* __restrict__ gend,
                        const float* __restrict__ Wlin, const float* __restrict__ blin,
                        float* __restrict__ out) {
    __shared__ float zs[BB * OUTC];
    const int t = threadIdx.x;  // 0..127
    const int g = t >> 1, o = t & 1;
    int cntg = gend[g] - gstart[g];
    if (cntg < 0) cntg = 0;
    const float inv = 1.0f / (float)max(cntg, 1);
    float z = blin[o];
    for (int k = 0; k < DD; k++)
        z += psum[g * DD + k] * inv * Wlin[k * OUTC + o];
    for (int k = 0; k < DD; k++)
        z += __uint_as_float(pmax[g * DD + k]) * Wlin[(DD + k) * OUTC + o];
    zs[t] = z;
    __syncthreads();
    float zo = zs[t ^ 1];
    float m = fmaxf(z, zo);
    float ls = m + logf(expf(z - m) + expf(zo - m));
    out[t] = z - ls;
}

extern "C" void kernel_launch(void* const* d_in, const int* in_sizes, int n_in,
                              void* d_out, int out_size, void* d_ws, size_t ws_size,
                              hipStream_t stream) {
    const float* x = (const float*)d_in[0];
    const int* ei = (const int*)d_in[1];
    const int* batch = (const int*)d_in[2];
    const int* sd = (const int*)d_in[3];
    const float* Wc = (const float*)d_in[4];
    const float* bc = (const float*)d_in[5];
    const float* gamma = (const float*)d_in[6];
    const float* beta = (const float*)d_in[7];
    const float* rmean = (const float*)d_in[8];
    const float* rvar = (const float*)d_in[9];
    const float* Wlin = (const float*)d_in[10];
    const float* blin = (const float*)d_in[11];
    float* out = (float*)d_out;

    char* p = (char*)d_ws;
    auto alloc = [&](size_t bytes) {
        char* r = p;
        p += (bytes + 255) & ~(size_t)255;
        return r;
    };
    float* hw = (float*)alloc((size_t)NN * DD * 4);
    unsigned short* Hhi = (unsigned short*)alloc((size_t)NN * DD * 2);
    unsigned short* Hlo = (unsigned short*)alloc((size_t)NN * DD * 2);
    unsigned short* WThi = (unsigned short*)alloc((size_t)LL * DD * DD * 2);
    unsigned short* WTlo = (unsigned short*)alloc((size_t)LL * DD * DD * 2);
    float* deg = (float*)alloc(NN * 4);
    float* dis = (float*)alloc(NN * 4);
    int* cnt = (int*)alloc(NN * 4);
    int* fill = (int*)alloc(NN * 4);
    int* rowptr = (int*)alloc((NN + 1) * 4);
    int* bsum = (int*)alloc(256 * 4);
    int* srcs = (int*)alloc(EE * 4);
    float* enorm = (float*)alloc(EE * 4);
    int* gstart = (int*)alloc(BB * 4);
    int* gend = (int*)alloc(BB * 4);
    float* psum = (float*)alloc(BB * DD * 4);
    unsigned int* pmax = (unsigned int*)alloc(BB * DD * 4);
    (void)ws_size; (void)in_sizes; (void)n_in; (void)out_size;

    const int nb256 = (NN + 255) / 256;          // 196
    const int eb256 = (EE + 255) / 256;          // 3125

    k_init<<<nb256, 256, 0, stream>>>(deg, cnt, fill, gstart, gend, psum, pmax);
    k_deg<<<eb256, 256, 0, stream>>>(ei, sd, deg, cnt);
    k_dis<<<nb256, 256, 0, stream>>>(deg, dis);
    k_scan1<<<nb256, 256, 0, stream>>>(cnt, rowptr, bsum);
    k_scan2<<<1, 1, 0, stream>>>(bsum, rowptr, nb256);
    k_scan3<<<nb256, 256, 0, stream>>>(rowptr, bsum);
    k_fill<<<eb256, 256, 0, stream>>>(ei, sd, dis, rowptr, fill, srcs, enorm);
    k_wt<<<(LL * DD * DD) / 256, 256, 0, stream>>>(Wc, WThi, WTlo);
    k_split<<<(NN * DD + 255) / 256, 256, 0, stream>>>(x, Hhi, Hlo, NN * DD);

    dim3 ggrid((NN + 63) / 64, DD / 64);  // (782, 8)
    for (int l = 0; l < LL; l++) {
        k_gemm<<<ggrid, 256, 0, stream>>>(Hhi, Hlo, WThi + (size_t)l * DD * DD,
                                          WTlo + (size_t)l * DD * DD, hw);
        k_agg<<<NN, 64, 0, stream>>>(hw, rowptr, srcs, enorm, dis,
                                     bc + l * DD, gamma + l * DD, beta + l * DD,
                                     rmean + l * DD, rvar + l * DD, Hhi, Hlo);
    }

    k_bounds<<<nb256, 256, 0, stream>>>(batch, gstart, gend);
    k_pool<<<dim3(BB, 8), 512, 0, stream>>>(Hhi, Hlo, gstart, gend, psum, pmax);
    k_final<<<1, BB * OUTC, 0, stream>>>(psum, pmax, gstart, gend, Wlin, blin, out);
}

// Round 2
// 2099.284 us; speedup vs baseline: 1.6619x; 1.6619x over previous
//
#include <hip/hip_runtime.h>
#include <hip/hip_bf16.h>

#define NN 50000
#define EE 800000
#define DD 512
#define BB 64
#define LL 4
#define OUTC 2
#define EPSV 1e-5f

#define MT 128
#define NT 128
#define BK 32

typedef __bf16 bf16x8 __attribute__((ext_vector_type(8)));
typedef float floatx4 __attribute__((ext_vector_type(4)));

__device__ __forceinline__ unsigned short f2bf(float x) {
    union { __hip_bfloat16 b; unsigned short u; } cv;
    cv.b = __float2bfloat16(x);
    return cv.u;
}
__device__ __forceinline__ float bf2f(unsigned short u) {
    union { __hip_bfloat16 b; unsigned short u; } cv;
    cv.u = u;
    return __bfloat162float(cv.b);
}

__device__ __forceinline__ floatx4 mfma16(bf16x8 a, bf16x8 b, floatx4 c) {
    return __builtin_amdgcn_mfma_f32_16x16x32_bf16(a, b, c, 0, 0, 0);
}

// async global->LDS, 16B per lane. LDS dest = wave-uniform base + lane*16;
// we pass per-thread pointers whose first-lane value is the wave base.
__device__ __forceinline__ void ldg2lds16(const unsigned short* g, unsigned short* l) {
    __builtin_amdgcn_global_load_lds(
        (const __attribute__((address_space(1))) unsigned int*)g,
        (__attribute__((address_space(3))) unsigned int*)l, 16, 0, 0);
}

// ---------------- init scratch ----------------
__global__ void k_init(float* deg, int* cnt, int* fill, int* gstart, int* gend,
                       float* psum, unsigned int* pmax) {
    int i = blockIdx.x * blockDim.x + threadIdx.x;
    if (i < NN) { deg[i] = 1.0f; cnt[i] = 0; fill[i] = 0; }
    if (i < BB) { gstart[i] = NN; gend[i] = 0; }
    if (i < BB * DD) { psum[i] = 0.f; pmax[i] = 0u; }
}

// ---------------- weighted degree + in-degree counts ----------------
__global__ void k_deg(const int* __restrict__ ei, const int* __restrict__ sd,
                      float* __restrict__ deg, int* __restrict__ cnt) {
    int e = blockIdx.x * blockDim.x + threadIdx.x;
    if (e >= EE) return;
    int c = ei[EE + e];
    float w = (sd[e] == 1) ? 1.0f : 0.7f;
    atomicAdd(&deg[c], w);
    atomicAdd(&cnt[c], 1);
}

__global__ void k_dis(const float* __restrict__ deg, float* __restrict__ dis) {
    int i = blockIdx.x * blockDim.x + threadIdx.x;
    if (i < NN) dis[i] = rsqrtf(fmaxf(deg[i], EPSV));
}

// ---------------- exclusive scan of counts -> rowptr ----------------
__global__ void k_scan1(const int* __restrict__ cnt, int* __restrict__ rowptr,
                        int* __restrict__ bsum) {
    __shared__ int sh[256];
    const int t = threadIdx.x;
    const int i = blockIdx.x * 256 + t;
    int v = (i < NN) ? cnt[i] : 0;
    sh[t] = v;
    __syncthreads();
    for (int off = 1; off < 256; off <<= 1) {
        int y = (t >= off) ? sh[t - off] : 0;
        __syncthreads();
        if (t >= off) sh[t] += y;
        __syncthreads();
    }
    if (i < NN) rowptr[i] = sh[t] - v;   // exclusive
    if (t == 255) bsum[blockIdx.x] = sh[255];
}

__global__ void k_scan2(int* __restrict__ bsum, int* __restrict__ rowptr, int nb) {
    if (threadIdx.x == 0 && blockIdx.x == 0) {
        int run = 0;
        for (int b = 0; b < nb; b++) { int t = bsum[b]; bsum[b] = run; run += t; }
        rowptr[NN] = run;
    }
}

__global__ void k_scan3(int* __restrict__ rowptr, const int* __restrict__ bsum) {
    int i = blockIdx.x * blockDim.x + threadIdx.x;
    if (i < NN) rowptr[i] += bsum[i >> 8];
}

// ---------------- CSR fill: per-dest src list + edge norm ----------------
__global__ void k_fill(const int* __restrict__ ei, const int* __restrict__ sd,
                       const float* __restrict__ dis, const int* __restrict__ rowptr,
                       int* __restrict__ fill, int* __restrict__ srcs,
                       float* __restrict__ enorm) {
    int e = blockIdx.x * blockDim.x + threadIdx.x;
    if (e >= EE) return;
    int s = ei[e];
    int c = ei[EE + e];
    float w = (sd[e] == 1) ? 1.0f : 0.7f;
    int p = rowptr[c] + atomicAdd(&fill[c], 1);
    srcs[p] = s;
    enorm[p] = dis[s] * w * dis[c];
}

// ---------------- weights: fp32 -> transposed bf16 hi/lo ----------------
__global__ void k_wt(const float* __restrict__ Wc, unsigned short* __restrict__ WThi,
                     unsigned short* __restrict__ WTlo) {
    int i = blockIdx.x * blockDim.x + threadIdx.x;  // < LL*DD*DD
    int l = i >> 18;
    int rem = i & ((DD * DD) - 1);
    int n = rem >> 9;
    int k = rem & (DD - 1);
    float v = Wc[(l << 18) + (k << 9) + n];
    unsigned short hb = f2bf(v);
    WThi[i] = hb;
    WTlo[i] = f2bf(v - bf2f(hb));
}

// ---------------- fp32 -> bf16 hi/lo split (layer-0 input x) ----------------
__global__ void k_split(const float* __restrict__ src, unsigned short* __restrict__ hi,
                        unsigned short* __restrict__ lo, int n) {
    int i = blockIdx.x * blockDim.x + threadIdx.x;
    if (i >= n) return;
    float v = src[i];
    unsigned short hb = f2bf(v);
    hi[i] = hb;
    lo[i] = f2bf(v - bf2f(hb));
}

// ---------------- GEMM: C[N,D] = (Ahi+Alo) @ (Bhi+Blo), m97-style LDS staging ------
// 128x128 tile, BK=32, 4 waves each computing 64x64 (4x4 16x16x32 frags),
// 3-term hi/lo split: Ah*Bh + Ah*Bl + Al*Bh.
__launch_bounds__(256)
__global__ void k_gemm(const unsigned short* __restrict__ Ahi,
                       const unsigned short* __restrict__ Alo,
                       const unsigned short* __restrict__ Bhi,
                       const unsigned short* __restrict__ Blo,
                       float* __restrict__ C) {
    __shared__ unsigned short sAh[MT * BK];
    __shared__ unsigned short sAl[MT * BK];
    __shared__ unsigned short sBh[NT * BK];
    __shared__ unsigned short sBl[NT * BK];

    const int t = threadIdx.x;
    const int wid = t >> 6;
    const int lane = t & 63;
    const int l15 = lane & 15;
    const int quad = lane >> 4;
    const int m0 = blockIdx.y * MT;
    const int n0 = blockIdx.x * NT;
    const int wr = (wid >> 1) * 64;   // wave row offset in tile
    const int wc = (wid & 1) * 64;    // wave col offset in tile

    // staging addresses: thread t covers tile-linear elements [t*8, t*8+8)
    // i.e. row t/4, k-offset (t%4)*8 of a [rows x BK] bf16 tile.
    const int srow = t >> 2;
    const int skoff = (t & 3) * 8;
    const unsigned short* gAh = Ahi + (size_t)(m0 + srow) * DD + skoff;
    const unsigned short* gAl = Alo + (size_t)(m0 + srow) * DD + skoff;
    const unsigned short* gBh = Bhi + (size_t)(n0 + srow) * DD + skoff;
    const unsigned short* gBl = Blo + (size_t)(n0 + srow) * DD + skoff;
    unsigned short* lA = sAh + t * 8;   // first-lane value is wave base
    unsigned short* lAl = sAl + t * 8;
    unsigned short* lB = sBh + t * 8;
    unsigned short* lBl = sBl + t * 8;

    floatx4 acc[4][4];
#pragma unroll
    for (int i = 0; i < 4; i++)
#pragma unroll
        for (int j = 0; j < 4; j++) acc[i][j] = (floatx4){0.f, 0.f, 0.f, 0.f};

    for (int k0 = 0; k0 < DD; k0 += BK) {
        __syncthreads();   // previous compute done before overwriting LDS
        // stage 4 tiles (each 64 rows per round, 2 rounds)
        ldg2lds16(gAh + k0, lA);
        ldg2lds16(gAh + 64 * DD + k0, lA + 64 * BK);
        ldg2lds16(gAl + k0, lAl);
        ldg2lds16(gAl + 64 * DD + k0, lAl + 64 * BK);
        ldg2lds16(gBh + k0, lB);
        ldg2lds16(gBh + 64 * DD + k0, lB + 64 * BK);
        ldg2lds16(gBl + k0, lBl);
        ldg2lds16(gBl + 64 * DD + k0, lBl + 64 * BK);
        __syncthreads();   // compiler drains vmcnt before barrier

        bf16x8 ah[4], al[4], bh[4], bl[4];
#pragma unroll
        for (int i = 0; i < 4; i++) {
            const int ar = (wr + i * 16 + l15) * BK + quad * 8;
            const int br = (wc + i * 16 + l15) * BK + quad * 8;
            ah[i] = *(const bf16x8*)&sAh[ar];
            al[i] = *(const bf16x8*)&sAl[ar];
            bh[i] = *(const bf16x8*)&sBh[br];
            bl[i] = *(const bf16x8*)&sBl[br];
        }
#pragma unroll
        for (int i = 0; i < 4; i++)
#pragma unroll
            for (int j = 0; j < 4; j++) {
                acc[i][j] = mfma16(ah[i], bh[j], acc[i][j]);
                acc[i][j] = mfma16(ah[i], bl[j], acc[i][j]);
                acc[i][j] = mfma16(al[i], bh[j], acc[i][j]);
            }
    }

#pragma unroll
    for (int i = 0; i < 4; i++) {
        const int rbase = m0 + wr + i * 16 + quad * 4;
#pragma unroll
        for (int j = 0; j < 4; j++) {
            const int gcol = n0 + wc + j * 16 + l15;
#pragma unroll
            for (int r = 0; r < 4; r++) {
                const int grow = rbase + r;
                if (grow < NN) C[(size_t)grow * DD + gcol] = acc[i][j][r];
            }
        }
    }
}

// ---------------- aggregate + bias + BN + ReLU + bf16 hi/lo split ----------------
__device__ __forceinline__ void bn_pack_store(
    float v0, float v1, float v2, float v3, int cidx,
    const float4* __restrict__ bc4, const float4* __restrict__ g4,
    const float4* __restrict__ b4, const float4* __restrict__ rm4,
    const float4* __restrict__ rv4, uint2* __restrict__ oh, uint2* __restrict__ ol) {
    float4 bcv = bc4[cidx], gv = g4[cidx], bv = b4[cidx], rmv = rm4[cidx], rvv = rv4[cidx];
    float h0 = fmaxf(gv.x * (v0 + bcv.x - rmv.x) * rsqrtf(rvv.x + EPSV) + bv.x, 0.f);
    float h1 = fmaxf(gv.y * (v1 + bcv.y - rmv.y) * rsqrtf(rvv.y + EPSV) + bv.y, 0.f);
    float h2 = fmaxf(gv.z * (v2 + bcv.z - rmv.z) * rsqrtf(rvv.z + EPSV) + bv.z, 0.f);
    float h3 = fmaxf(gv.w * (v3 + bcv.w - rmv.w) * rsqrtf(rvv.w + EPSV) + bv.w, 0.f);
    unsigned short p0 = f2bf(h0), p1 = f2bf(h1), p2 = f2bf(h2), p3 = f2bf(h3);
    uint2 uh;
    uh.x = (unsigned)p0 | ((unsigned)p1 << 16);
    uh.y = (unsigned)p2 | ((unsigned)p3 << 16);
    unsigned short q0 = f2bf(h0 - bf2f(p0)), q1 = f2bf(h1 - bf2f(p1));
    unsigned short q2 = f2bf(h2 - bf2f(p2)), q3 = f2bf(h3 - bf2f(p3));
    uint2 ul;
    ul.x = (unsigned)q0 | ((unsigned)q1 << 16);
    ul.y = (unsigned)q2 | ((unsigned)q3 << 16);
    oh[cidx] = uh;
    ol[cidx] = ul;
}

__launch_bounds__(64)
__global__ void k_agg(const float* __restrict__ hw, const int* __restrict__ rowptr,
                      const int* __restrict__ srcs, const float* __restrict__ enorm,
                      const float* __restrict__ dis,
                      const float* __restrict__ bcl, const float* __restrict__ gl,
                      const float* __restrict__ bl_, const float* __restrict__ rml,
                      const float* __restrict__ rvl,
                      unsigned short* __restrict__ Hhi, unsigned short* __restrict__ Hlo) {
    const int n = blockIdx.x;
    const int lane = threadIdx.x;
    const float4* rowp = (const float4*)(hw + (size_t)n * DD);
    const float dn = dis[n];
    const float sw = dn * dn;  // self-loop norm
    float4 a0 = rowp[lane];
    float4 a1 = rowp[lane + 64];
    float x0 = a0.x * sw, x1 = a0.y * sw, x2 = a0.z * sw, x3 = a0.w * sw;
    float y0 = a1.x * sw, y1 = a1.y * sw, y2 = a1.z * sw, y3 = a1.w * sw;
    const int s0 = rowptr[n], s1 = rowptr[n + 1];
    int i = s0;
    // 2-edge unrolled main loop: 4 independent 16B loads in flight per lane
    for (; i + 2 <= s1; i += 2) {
        const int sa = srcs[i];
        const int sb = srcs[i + 1];
        const float wa = enorm[i];
        const float wb = enorm[i + 1];
        const float4* ra = (const float4*)(hw + (size_t)sa * DD);
        const float4* rb = (const float4*)(hw + (size_t)sb * DD);
        float4 pa0 = ra[lane];
        float4 pa1 = ra[lane + 64];
        float4 pb0 = rb[lane];
        float4 pb1 = rb[lane + 64];
        x0 = fmaf(pa0.x, wa, x0); x1 = fmaf(pa0.y, wa, x1);
        x2 = fmaf(pa0.z, wa, x2); x3 = fmaf(pa0.w, wa, x3);
        y0 = fmaf(pa1.x, wa, y0); y1 = fmaf(pa1.y, wa, y1);
        y2 = fmaf(pa1.z, wa, y2); y3 = fmaf(pa1.w, wa, y3);
        x0 = fmaf(pb0.x, wb, x0); x1 = fmaf(pb0.y, wb, x1);
        x2 = fmaf(pb0.z, wb, x2); x3 = fmaf(pb0.w, wb, x3);
        y0 = fmaf(pb1.x, wb, y0); y1 = fmaf(pb1.y, wb, y1);
        y2 = fmaf(pb1.z, wb, y2); y3 = fmaf(pb1.w, wb, y3);
    }
    if (i < s1) {
        const int s = srcs[i];
        const float wn = enorm[i];
        const float4* rp = (const float4*)(hw + (size_t)s * DD);
        float4 b0 = rp[lane];
        float4 b1 = rp[lane + 64];
        x0 = fmaf(b0.x, wn, x0); x1 = fmaf(b0.y, wn, x1);
        x2 = fmaf(b0.z, wn, x2); x3 = fmaf(b0.w, wn, x3);
        y0 = fmaf(b1.x, wn, y0); y1 = fmaf(b1.y, wn, y1);
        y2 = fmaf(b1.z, wn, y2); y3 = fmaf(b1.w, wn, y3);
    }
    const float4* bc4 = (const float4*)bcl;
    const float4* g4 = (const float4*)gl;
    const float4* b4 = (const float4*)bl_;
    const float4* rm4 = (const float4*)rml;
    const float4* rv4 = (const float4*)rvl;
    uint2* oh = (uint2*)(Hhi + (size_t)n * DD);
    uint2* ol = (uint2*)(Hlo + (size_t)n * DD);
    bn_pack_store(x0, x1, x2, x3, lane, bc4, g4, b4, rm4, rv4, oh, ol);
    bn_pack_store(y0, y1, y2, y3, lane + 64, bc4, g4, b4, rm4, rv4, oh, ol);
}

// ---------------- graph node ranges (batch is sorted) ----------------
__global__ void k_bounds(const int* __restrict__ batch, int* __restrict__ gstart,
                         int* __restrict__ gend) {
    int n = blockIdx.x * blockDim.x + threadIdx.x;
    if (n >= NN) return;
    int g = batch[n];
    atomicMin(&gstart[g], n);
    atomicMax(&gend[g], n + 1);
}

// ---------------- mean/max pooling (8 slices per graph) ----------------
__launch_bounds__(512)
__global__ void k_pool(const unsigned short* __restrict__ Hhi,
                       const unsigned short* __restrict__ Hlo,
                       const int* __restrict__ gstart, const int* __restrict__ gend,
                       float* __restrict__ psum, unsigned int* __restrict__ pmax) {
    const int g = blockIdx.x;
    const int sl = blockIdx.y;
    const int c = threadIdx.x;
    const int s0 = gstart[g], e0 = gend[g];
    if (e0 <= s0) return;
    const int len = e0 - s0;
    const int chunk = (len + 7) >> 3;
    const int lo = s0 + sl * chunk;
    const int hi = min(lo + chunk, e0);
    float sum = 0.f, mx = 0.f;
    for (int n = lo; n < hi; n++) {
        float v = bf2f(Hhi[(size_t)n * DD + c]) + bf2f(Hlo[(size_t)n * DD + c]);
        sum += v;
        mx = fmaxf(mx, v);
    }
    if (lo < hi) {
        atomicAdd(&psum[g * DD + c], sum);
        atomicMax(&pmax[g * DD + c], __float_as_uint(fmaxf(mx, 0.f)));  // h >= 0
    }
}

// ---------------- final linear + log_softmax ----------------
__global__ void k_final(const float* __restrict__ psum, const unsigned int* __restrict__ pmax,
                        const int* __restrict__ gstart, const int* __restrict__ gend,
                        const float* __restrict__ Wlin, const float* __restrict__ blin,
                        float* __restrict__ out) {
    __shared__ float zs[BB * OUTC];
    const int t = threadIdx.x;  // 0..127
    const int g = t >> 1, o = t & 1;
    int cntg = gend[g] - gstart[g];
    if (cntg < 0) cntg = 0;
    const float inv = 1.0f / (float)max(cntg, 1);
    float z = blin[o];
    for (int k = 0; k < DD; k++)
        z += psum[g * DD + k] * inv * Wlin[k * OUTC + o];
    for (int k = 0; k < DD; k++)
        z += __uint_as_float(pmax[g * DD + k]) * Wlin[(DD + k) * OUTC + o];
    zs[t] = z;
    __syncthreads();
    float zo = zs[t ^ 1];
    float m = fmaxf(z, zo);
    float ls = m + logf(expf(z - m) + expf(zo - m));
    out[t] = z - ls;
}

extern "C" void kernel_launch(void* const* d_in, const int* in_sizes, int n_in,
                              void* d_out, int out_size, void* d_ws, size_t ws_size,
                              hipStream_t stream) {
    const float* x = (const float*)d_in[0];
    const int* ei = (const int*)d_in[1];
    const int* batch = (const int*)d_in[2];
    const int* sd = (const int*)d_in[3];
    const float* Wc = (const float*)d_in[4];
    const float* bc = (const float*)d_in[5];
    const float* gamma = (const float*)d_in[6];
    const float* beta = (const float*)d_in[7];
    const float* rmean = (const float*)d_in[8];
    const float* rvar = (const float*)d_in[9];
    const float* Wlin = (const float*)d_in[10];
    const float* blin = (const float*)d_in[11];
    float* out = (float*)d_out;

    char* p = (char*)d_ws;
    auto alloc = [&](size_t bytes) {
        char* r = p;
        p += (bytes + 255) & ~(size_t)255;
        return r;
    };
    float* hw = (float*)alloc((size_t)NN * DD * 4);
    unsigned short* Hhi = (unsigned short*)alloc((size_t)NN * DD * 2);
    unsigned short* Hlo = (unsigned short*)alloc((size_t)NN * DD * 2);
    unsigned short* WThi = (unsigned short*)alloc((size_t)LL * DD * DD * 2);
    unsigned short* WTlo = (unsigned short*)alloc((size_t)LL * DD * DD * 2);
    float* deg = (float*)alloc(NN * 4);
    float* dis = (float*)alloc(NN * 4);
    int* cnt = (int*)alloc(NN * 4);
    int* fill = (int*)alloc(NN * 4);
    int* rowptr = (int*)alloc((NN + 1) * 4);
    int* bsum = (int*)alloc(256 * 4);
    int* srcs = (int*)alloc(EE * 4);
    float* enorm = (float*)alloc(EE * 4);
    int* gstart = (int*)alloc(BB * 4);
    int* gend = (int*)alloc(BB * 4);
    float* psum = (float*)alloc(BB * DD * 4);
    unsigned int* pmax = (unsigned int*)alloc(BB * DD * 4);
    (void)ws_size; (void)in_sizes; (void)n_in; (void)out_size;

    const int nb256 = (NN + 255) / 256;          // 196
    const int eb256 = (EE + 255) / 256;          // 3125

    k_init<<<nb256, 256, 0, stream>>>(deg, cnt, fill, gstart, gend, psum, pmax);
    k_deg<<<eb256, 256, 0, stream>>>(ei, sd, deg, cnt);
    k_dis<<<nb256, 256, 0, stream>>>(deg, dis);
    k_scan1<<<nb256, 256, 0, stream>>>(cnt, rowptr, bsum);
    k_scan2<<<1, 1, 0, stream>>>(bsum, rowptr, nb256);
    k_scan3<<<nb256, 256, 0, stream>>>(rowptr, bsum);
    k_fill<<<eb256, 256, 0, stream>>>(ei, sd, dis, rowptr, fill, srcs, enorm);
    k_wt<<<(LL * DD * DD) / 256, 256, 0, stream>>>(Wc, WThi, WTlo);
    k_split<<<(NN * DD + 255) / 256, 256, 0, stream>>>(x, Hhi, Hlo, NN * DD);

    // n-tile fastest so co-resident blocks share A slabs in L2/L3
    dim3 ggrid(DD / NT, (NN + MT - 1) / MT);  // (4, 391)
    for (int l = 0; l < LL; l++) {
        k_gemm<<<ggrid, 256, 0, stream>>>(Hhi, Hlo, WThi + (size_t)l * DD * DD,
                                          WTlo + (size_t)l * DD * DD, hw);
        k_agg<<<NN, 64, 0, stream>>>(hw, rowptr, srcs, enorm, dis,
                                     bc + l * DD, gamma + l * DD, beta + l * DD,
                                     rmean + l * DD, rvar + l * DD, Hhi, Hlo);
    }

    k_bounds<<<nb256, 256, 0, stream>>>(batch, gstart, gend);
    k_pool<<<dim3(BB, 8), 512, 0, stream>>>(Hhi, Hlo, gstart, gend, psum, pmax);
    k_final<<<1, BB * OUTC, 0, stream>>>(psum, pmax, gstart, gend, Wlin, blin, out);
}

// Round 3
// 1812.790 us; speedup vs baseline: 1.9245x; 1.1580x over previous
//
#include <hip/hip_runtime.h>
#include <hip/hip_bf16.h>

#define NN 50000
#define EE 800000
#define DD 512
#define BB 64
#define LL 4
#define OUTC 2
#define EPSV 1e-5f

#define MT 128
#define NT 128
#define BK 32

typedef __bf16 bf16x8 __attribute__((ext_vector_type(8)));
typedef float floatx4 __attribute__((ext_vector_type(4)));

__device__ __forceinline__ unsigned short f2bf(float x) {
    union { __hip_bfloat16 b; unsigned short u; } cv;
    cv.b = __float2bfloat16(x);
    return cv.u;
}
__device__ __forceinline__ float bf2f(unsigned short u) {
    union { __hip_bfloat16 b; unsigned short u; } cv;
    cv.u = u;
    return __bfloat162float(cv.b);
}

__device__ __forceinline__ floatx4 mfma16(bf16x8 a, bf16x8 b, floatx4 c) {
    return __builtin_amdgcn_mfma_f32_16x16x32_bf16(a, b, c, 0, 0, 0);
}

// async global->LDS, 16B per lane. LDS dest = wave-uniform base + lane*16;
// we pass per-thread pointers whose first-lane value is the wave base.
__device__ __forceinline__ void ldg2lds16(const unsigned short* g, unsigned short* l) {
    __builtin_amdgcn_global_load_lds(
        (const __attribute__((address_space(1))) unsigned int*)g,
        (__attribute__((address_space(3))) unsigned int*)l, 16, 0, 0);
}

// ---------------- init scratch ----------------
__global__ void k_init(float* deg, int* cnt, int* fill, int* gstart, int* gend,
                       float* psum, unsigned int* pmax) {
    int i = blockIdx.x * blockDim.x + threadIdx.x;
    if (i < NN) { deg[i] = 1.0f; cnt[i] = 0; fill[i] = 0; }
    if (i < BB) { gstart[i] = NN; gend[i] = 0; }
    if (i < BB * DD) { psum[i] = 0.f; pmax[i] = 0u; }
}

// ---------------- weighted degree + in-degree counts ----------------
__global__ void k_deg(const int* __restrict__ ei, const int* __restrict__ sd,
                      float* __restrict__ deg, int* __restrict__ cnt) {
    int e = blockIdx.x * blockDim.x + threadIdx.x;
    if (e >= EE) return;
    int c = ei[EE + e];
    float w = (sd[e] == 1) ? 1.0f : 0.7f;
    atomicAdd(&deg[c], w);
    atomicAdd(&cnt[c], 1);
}

__global__ void k_dis(const float* __restrict__ deg, float* __restrict__ dis) {
    int i = blockIdx.x * blockDim.x + threadIdx.x;
    if (i < NN) dis[i] = rsqrtf(fmaxf(deg[i], EPSV));
}

// ---------------- exclusive scan of counts -> rowptr ----------------
__global__ void k_scan1(const int* __restrict__ cnt, int* __restrict__ rowptr,
                        int* __restrict__ bsum) {
    __shared__ int sh[256];
    const int t = threadIdx.x;
    const int i = blockIdx.x * 256 + t;
    int v = (i < NN) ? cnt[i] : 0;
    sh[t] = v;
    __syncthreads();
    for (int off = 1; off < 256; off <<= 1) {
        int y = (t >= off) ? sh[t - off] : 0;
        __syncthreads();
        if (t >= off) sh[t] += y;
        __syncthreads();
    }
    if (i < NN) rowptr[i] = sh[t] - v;   // exclusive
    if (t == 255) bsum[blockIdx.x] = sh[255];
}

__global__ void k_scan2(int* __restrict__ bsum, int* __restrict__ rowptr, int nb) {
    if (threadIdx.x == 0 && blockIdx.x == 0) {
        int run = 0;
        for (int b = 0; b < nb; b++) { int t = bsum[b]; bsum[b] = run; run += t; }
        rowptr[NN] = run;
    }
}

__global__ void k_scan3(int* __restrict__ rowptr, const int* __restrict__ bsum) {
    int i = blockIdx.x * blockDim.x + threadIdx.x;
    if (i < NN) rowptr[i] += bsum[i >> 8];
}

// ---------------- CSR fill: per-dest src list + edge norm ----------------
__global__ void k_fill(const int* __restrict__ ei, const int* __restrict__ sd,
                       const float* __restrict__ dis, const int* __restrict__ rowptr,
                       int* __restrict__ fill, int* __restrict__ srcs,
                       float* __restrict__ enorm) {
    int e = blockIdx.x * blockDim.x + threadIdx.x;
    if (e >= EE) return;
    int s = ei[e];
    int c = ei[EE + e];
    float w = (sd[e] == 1) ? 1.0f : 0.7f;
    int p = rowptr[c] + atomicAdd(&fill[c], 1);
    srcs[p] = s;
    enorm[p] = dis[s] * w * dis[c];
}

// ---------------- weights: fp32 -> transposed bf16 hi/lo ----------------
__global__ void k_wt(const float* __restrict__ Wc, unsigned short* __restrict__ WThi,
                     unsigned short* __restrict__ WTlo) {
    int i = blockIdx.x * blockDim.x + threadIdx.x;  // < LL*DD*DD
    int l = i >> 18;
    int rem = i & ((DD * DD) - 1);
    int n = rem >> 9;
    int k = rem & (DD - 1);
    float v = Wc[(l << 18) + (k << 9) + n];
    unsigned short hb = f2bf(v);
    WThi[i] = hb;
    WTlo[i] = f2bf(v - bf2f(hb));
}

// ---------------- fp32 -> bf16 hi/lo split (layer-0 input x) ----------------
__global__ void k_split(const float* __restrict__ src, unsigned short* __restrict__ hi,
                        unsigned short* __restrict__ lo, int n) {
    int i = blockIdx.x * blockDim.x + threadIdx.x;
    if (i >= n) return;
    float v = src[i];
    unsigned short hb = f2bf(v);
    hi[i] = hb;
    lo[i] = f2bf(v - bf2f(hb));
}

// ---------------- GEMM: C[N,D] = (Ahi+Alo) @ (Bhi+Blo), m97-style LDS staging ------
// 128x128 tile, BK=32, 4 waves each computing 64x64 (4x4 16x16x32 frags),
// 3-term hi/lo split: Ah*Bh + Ah*Bl + Al*Bh.
__launch_bounds__(256)
__global__ void k_gemm(const unsigned short* __restrict__ Ahi,
                       const unsigned short* __restrict__ Alo,
                       const unsigned short* __restrict__ Bhi,
                       const unsigned short* __restrict__ Blo,
                       float* __restrict__ C) {
    __shared__ unsigned short sAh[MT * BK];
    __shared__ unsigned short sAl[MT * BK];
    __shared__ unsigned short sBh[NT * BK];
    __shared__ unsigned short sBl[NT * BK];

    const int t = threadIdx.x;
    const int wid = t >> 6;
    const int lane = t & 63;
    const int l15 = lane & 15;
    const int quad = lane >> 4;
    const int m0 = blockIdx.y * MT;
    const int n0 = blockIdx.x * NT;
    const int wr = (wid >> 1) * 64;   // wave row offset in tile
    const int wc = (wid & 1) * 64;    // wave col offset in tile

    // staging addresses: thread t covers tile-linear elements [t*8, t*8+8)
    // i.e. row t/4, k-offset (t%4)*8 of a [rows x BK] bf16 tile.
    const int srow = t >> 2;
    const int skoff = (t & 3) * 8;
    const unsigned short* gAh = Ahi + (size_t)(m0 + srow) * DD + skoff;
    const unsigned short* gAl = Alo + (size_t)(m0 + srow) * DD + skoff;
    const unsigned short* gBh = Bhi + (size_t)(n0 + srow) * DD + skoff;
    const unsigned short* gBl = Blo + (size_t)(n0 + srow) * DD + skoff;
    unsigned short* lA = sAh + t * 8;   // first-lane value is wave base
    unsigned short* lAl = sAl + t * 8;
    unsigned short* lB = sBh + t * 8;
    unsigned short* lBl = sBl + t * 8;

    floatx4 acc[4][4];
#pragma unroll
    for (int i = 0; i < 4; i++)
#pragma unroll
        for (int j = 0; j < 4; j++) acc[i][j] = (floatx4){0.f, 0.f, 0.f, 0.f};

    for (int k0 = 0; k0 < DD; k0 += BK) {
        __syncthreads();   // previous compute done before overwriting LDS
        // stage 4 tiles (each 64 rows per round, 2 rounds)
        ldg2lds16(gAh + k0, lA);
        ldg2lds16(gAh + 64 * DD + k0, lA + 64 * BK);
        ldg2lds16(gAl + k0, lAl);
        ldg2lds16(gAl + 64 * DD + k0, lAl + 64 * BK);
        ldg2lds16(gBh + k0, lB);
        ldg2lds16(gBh + 64 * DD + k0, lB + 64 * BK);
        ldg2lds16(gBl + k0, lBl);
        ldg2lds16(gBl + 64 * DD + k0, lBl + 64 * BK);
        __syncthreads();   // compiler drains vmcnt before barrier

        bf16x8 ah[4], al[4], bh[4], bl[4];
#pragma unroll
        for (int i = 0; i < 4; i++) {
            const int ar = (wr + i * 16 + l15) * BK + quad * 8;
            const int br = (wc + i * 16 + l15) * BK + quad * 8;
            ah[i] = *(const bf16x8*)&sAh[ar];
            al[i] = *(const bf16x8*)&sAl[ar];
            bh[i] = *(const bf16x8*)&sBh[br];
            bl[i] = *(const bf16x8*)&sBl[br];
        }
#pragma unroll
        for (int i = 0; i < 4; i++)
#pragma unroll
            for (int j = 0; j < 4; j++) {
                acc[i][j] = mfma16(ah[i], bh[j], acc[i][j]);
                acc[i][j] = mfma16(ah[i], bl[j], acc[i][j]);
                acc[i][j] = mfma16(al[i], bh[j], acc[i][j]);
            }
    }

#pragma unroll
    for (int i = 0; i < 4; i++) {
        const int rbase = m0 + wr + i * 16 + quad * 4;
#pragma unroll
        for (int j = 0; j < 4; j++) {
            const int gcol = n0 + wc + j * 16 + l15;
#pragma unroll
            for (int r = 0; r < 4; r++) {
                const int grow = rbase + r;
                if (grow < NN) C[(size_t)grow * DD + gcol] = acc[i][j][r];
            }
        }
    }
}

// ---------------- aggregate + bias + BN + ReLU + bf16 hi/lo split ----------------
__device__ __forceinline__ void bn_pack_store(
    float v0, float v1, float v2, float v3, int cidx,
    const float4* __restrict__ bc4, const float4* __restrict__ g4,
    const float4* __restrict__ b4, const float4* __restrict__ rm4,
    const float4* __restrict__ rv4, uint2* __restrict__ oh, uint2* __restrict__ ol) {
    float4 bcv = bc4[cidx], gv = g4[cidx], bv = b4[cidx], rmv = rm4[cidx], rvv = rv4[cidx];
    float h0 = fmaxf(gv.x * (v0 + bcv.x - rmv.x) * rsqrtf(rvv.x + EPSV) + bv.x, 0.f);
    float h1 = fmaxf(gv.y * (v1 + bcv.y - rmv.y) * rsqrtf(rvv.y + EPSV) + bv.y, 0.f);
    float h2 = fmaxf(gv.z * (v2 + bcv.z - rmv.z) * rsqrtf(rvv.z + EPSV) + bv.z, 0.f);
    float h3 = fmaxf(gv.w * (v3 + bcv.w - rmv.w) * rsqrtf(rvv.w + EPSV) + bv.w, 0.f);
    unsigned short p0 = f2bf(h0), p1 = f2bf(h1), p2 = f2bf(h2), p3 = f2bf(h3);
    uint2 uh;
    uh.x = (unsigned)p0 | ((unsigned)p1 << 16);
    uh.y = (unsigned)p2 | ((unsigned)p3 << 16);
    unsigned short q0 = f2bf(h0 - bf2f(p0)), q1 = f2bf(h1 - bf2f(p1));
    unsigned short q2 = f2bf(h2 - bf2f(p2)), q3 = f2bf(h3 - bf2f(p3));
    uint2 ul;
    ul.x = (unsigned)q0 | ((unsigned)q1 << 16);
    ul.y = (unsigned)q2 | ((unsigned)q3 << 16);
    oh[cidx] = uh;
    ol[cidx] = ul;
}

__launch_bounds__(64)
__global__ void k_agg(const float* __restrict__ hw, const int* __restrict__ rowptr,
                      const int* __restrict__ srcs, const float* __restrict__ enorm,
                      const float* __restrict__ dis,
                      const float* __restrict__ bcl, const float* __restrict__ gl,
                      const float* __restrict__ bl_, const float* __restrict__ rml,
                      const float* __restrict__ rvl,
                      unsigned short* __restrict__ Hhi, unsigned short* __restrict__ Hlo) {
    const int n = blockIdx.x;
    const int lane = threadIdx.x;
    const float4* rowp = (const float4*)(hw + (size_t)n * DD);
    const float dn = dis[n];
    const float sw = dn * dn;  // self-loop norm
    float4 a0 = rowp[lane];
    float4 a1 = rowp[lane + 64];
    float x0 = a0.x * sw, x1 = a0.y * sw, x2 = a0.z * sw, x3 = a0.w * sw;
    float y0 = a1.x * sw, y1 = a1.y * sw, y2 = a1.z * sw, y3 = a1.w * sw;
    const int s0 = rowptr[n], s1 = rowptr[n + 1];
    int i = s0;
    // 2-edge unrolled main loop: 4 independent 16B loads in flight per lane
    for (; i + 2 <= s1; i += 2) {
        const int sa = srcs[i];
        const int sb = srcs[i + 1];
        const float wa = enorm[i];
        const float wb = enorm[i + 1];
        const float4* ra = (const float4*)(hw + (size_t)sa * DD);
        const float4* rb = (const float4*)(hw + (size_t)sb * DD);
        float4 pa0 = ra[lane];
        float4 pa1 = ra[lane + 64];
        float4 pb0 = rb[lane];
        float4 pb1 = rb[lane + 64];
        x0 = fmaf(pa0.x, wa, x0); x1 = fmaf(pa0.y, wa, x1);
        x2 = fmaf(pa0.z, wa, x2); x3 = fmaf(pa0.w, wa, x3);
        y0 = fmaf(pa1.x, wa, y0); y1 = fmaf(pa1.y, wa, y1);
        y2 = fmaf(pa1.z, wa, y2); y3 = fmaf(pa1.w, wa, y3);
        x0 = fmaf(pb0.x, wb, x0); x1 = fmaf(pb0.y, wb, x1);
        x2 = fmaf(pb0.z, wb, x2); x3 = fmaf(pb0.w, wb, x3);
        y0 = fmaf(pb1.x, wb, y0); y1 = fmaf(pb1.y, wb, y1);
        y2 = fmaf(pb1.z, wb, y2); y3 = fmaf(pb1.w, wb, y3);
    }
    if (i < s1) {
        const int s = srcs[i];
        const float wn = enorm[i];
        const float4* rp = (const float4*)(hw + (size_t)s * DD);
        float4 b0 = rp[lane];
        float4 b1 = rp[lane + 64];
        x0 = fmaf(b0.x, wn, x0); x1 = fmaf(b0.y, wn, x1);
        x2 = fmaf(b0.z, wn, x2); x3 = fmaf(b0.w, wn, x3);
        y0 = fmaf(b1.x, wn, y0); y1 = fmaf(b1.y, wn, y1);
        y2 = fmaf(b1.z, wn, y2); y3 = fmaf(b1.w, wn, y3);
    }
    const float4* bc4 = (const float4*)bcl;
    const float4* g4 = (const float4*)gl;
    const float4* b4 = (const float4*)bl_;
    const float4* rm4 = (const float4*)rml;
    const float4* rv4 = (const float4*)rvl;
    uint2* oh = (uint2*)(Hhi + (size_t)n * DD);
    uint2* ol = (uint2*)(Hlo + (size_t)n * DD);
    bn_pack_store(x0, x1, x2, x3, lane, bc4, g4, b4, rm4, rv4, oh, ol);
    bn_pack_store(y0, y1, y2, y3, lane + 64, bc4, g4, b4, rm4, rv4, oh, ol);
}

// ---------------- graph node ranges (batch is sorted -> boundary detection, NO atomics) ----
__global__ void k_bounds(const int* __restrict__ batch, int* __restrict__ gstart,
                         int* __restrict__ gend) {
    int n = blockIdx.x * blockDim.x + threadIdx.x;
    if (n >= NN) return;
    int g = batch[n];
    int gp = (n == 0) ? -1 : batch[n - 1];
    if (g != gp) gstart[g] = n;          // first node of graph g
    int gn = (n == NN - 1) ? BB : batch[n + 1];
    if (g != gn) gend[g] = n + 1;        // one past last node of graph g
}

// ---------------- mean/max pooling (8 slices per graph) ----------------
__launch_bounds__(512)
__global__ void k_pool(const unsigned short* __restrict__ Hhi,
                       const unsigned short* __restrict__ Hlo,
                       const int* __restrict__ gstart, const int* __restrict__ gend,
                       float* __restrict__ psum, unsigned int* __restrict__ pmax) {
    const int g = blockIdx.x;
    const int sl = blockIdx.y;
    const int c = threadIdx.x;
    const int s0 = gstart[g], e0 = gend[g];
    if (e0 <= s0) return;
    const int len = e0 - s0;
    const int chunk = (len + 7) >> 3;
    const int lo = s0 + sl * chunk;
    const int hi = min(lo + chunk, e0);
    float sum = 0.f, mx = 0.f;
    for (int n = lo; n < hi; n++) {
        float v = bf2f(Hhi[(size_t)n * DD + c]) + bf2f(Hlo[(size_t)n * DD + c]);
        sum += v;
        mx = fmaxf(mx, v);
    }
    if (lo < hi) {
        atomicAdd(&psum[g * DD + c], sum);
        atomicMax(&pmax[g * DD + c], __float_as_uint(fmaxf(mx, 0.f)));  // h >= 0
    }
}

// ---------------- final linear + log_softmax ----------------
__global__ void k_final(const float* __restrict__ psum, const unsigned int* __restrict__ pmax,
                        const int* __restrict__ gstart, const int* __restrict__ gend,
                        const float* __restrict__ Wlin, const float* __restrict__ blin,
                        float* __restrict__ out) {
    __shared__ float zs[BB * OUTC];
    const int t = threadIdx.x;  // 0..127
    const int g = t >> 1, o = t & 1;
    int cntg = gend[g] - gstart[g];
    if (cntg < 0) cntg = 0;
    const float inv = 1.0f / (float)max(cntg, 1);
    float z = blin[o];
    for (int k = 0; k < DD; k++)
        z += psum[g * DD + k] * inv * Wlin[k * OUTC + o];
    for (int k = 0; k < DD; k++)
        z += __uint_as_float(pmax[g * DD + k]) * Wlin[(DD + k) * OUTC + o];
    zs[t] = z;
    __syncthreads();
    float zo = zs[t ^ 1];
    float m = fmaxf(z, zo);
    float ls = m + logf(expf(z - m) + expf(zo - m));
    out[t] = z - ls;
}

extern "C" void kernel_launch(void* const* d_in, const int* in_sizes, int n_in,
                              void* d_out, int out_size, void* d_ws, size_t ws_size,
                              hipStream_t stream) {
    const float* x = (const float*)d_in[0];
    const int* ei = (const int*)d_in[1];
    const int* batch = (const int*)d_in[2];
    const int* sd = (const int*)d_in[3];
    const float* Wc = (const float*)d_in[4];
    const float* bc = (const float*)d_in[5];
    const float* gamma = (const float*)d_in[6];
    const float* beta = (const float*)d_in[7];
    const float* rmean = (const float*)d_in[8];
    const float* rvar = (const float*)d_in[9];
    const float* Wlin = (const float*)d_in[10];
    const float* blin = (const float*)d_in[11];
    float* out = (float*)d_out;

    char* p = (char*)d_ws;
    auto alloc = [&](size_t bytes) {
        char* r = p;
        p += (bytes + 255) & ~(size_t)255;
        return r;
    };
    float* hw = (float*)alloc((size_t)NN * DD * 4);
    unsigned short* Hhi = (unsigned short*)alloc((size_t)NN * DD * 2);
    unsigned short* Hlo = (unsigned short*)alloc((size_t)NN * DD * 2);
    unsigned short* WThi = (unsigned short*)alloc((size_t)LL * DD * DD * 2);
    unsigned short* WTlo = (unsigned short*)alloc((size_t)LL * DD * DD * 2);
    float* deg = (float*)alloc(NN * 4);
    float* dis = (float*)alloc(NN * 4);
    int* cnt = (int*)alloc(NN * 4);
    int* fill = (int*)alloc(NN * 4);
    int* rowptr = (int*)alloc((NN + 1) * 4);
    int* bsum = (int*)alloc(256 * 4);
    int* srcs = (int*)alloc(EE * 4);
    float* enorm = (float*)alloc(EE * 4);
    int* gstart = (int*)alloc(BB * 4);
    int* gend = (int*)alloc(BB * 4);
    float* psum = (float*)alloc(BB * DD * 4);
    unsigned int* pmax = (unsigned int*)alloc(BB * DD * 4);
    (void)ws_size; (void)in_sizes; (void)n_in; (void)out_size;

    const int nb256 = (NN + 255) / 256;          // 196
    const int eb256 = (EE + 255) / 256;          // 3125

    k_init<<<nb256, 256, 0, stream>>>(deg, cnt, fill, gstart, gend, psum, pmax);
    k_deg<<<eb256, 256, 0, stream>>>(ei, sd, deg, cnt);
    k_dis<<<nb256, 256, 0, stream>>>(deg, dis);
    k_scan1<<<nb256, 256, 0, stream>>>(cnt, rowptr, bsum);
    k_scan2<<<1, 1, 0, stream>>>(bsum, rowptr, nb256);
    k_scan3<<<nb256, 256, 0, stream>>>(rowptr, bsum);
    k_fill<<<eb256, 256, 0, stream>>>(ei, sd, dis, rowptr, fill, srcs, enorm);
    k_wt<<<(LL * DD * DD) / 256, 256, 0, stream>>>(Wc, WThi, WTlo);
    k_split<<<(NN * DD + 255) / 256, 256, 0, stream>>>(x, Hhi, Hlo, NN * DD);

    // n-tile fastest so co-resident blocks share A slabs in L2/L3
    dim3 ggrid(DD / NT, (NN + MT - 1) / MT);  // (4, 391)
    for (int l = 0; l < LL; l++) {
        k_gemm<<<ggrid, 256, 0, stream>>>(Hhi, Hlo, WThi + (size_t)l * DD * DD,
                                          WTlo + (size_t)l * DD * DD, hw);
        k_agg<<<NN, 64, 0, stream>>>(hw, rowptr, srcs, enorm, dis,
                                     bc + l * DD, gamma + l * DD, beta + l * DD,
                                     rmean + l * DD, rvar + l * DD, Hhi, Hlo);
    }

    k_bounds<<<nb256, 256, 0, stream>>>(batch, gstart, gend);
    k_pool<<<dim3(BB, 8), 512, 0, stream>>>(Hhi, Hlo, gstart, gend, psum, pmax);
    k_final<<<1, BB * OUTC, 0, stream>>>(psum, pmax, gstart, gend, Wlin, blin, out);
}

// Round 4
// 1346.490 us; speedup vs baseline: 2.5910x; 1.3463x over previous
//
#include <hip/hip_runtime.h>
#include <hip/hip_bf16.h>

#define NN 50000
#define EE 800000
#define DD 512
#define BB 64
#define LL 4
#define OUTC 2
#define EPSV 1e-5f

#define MT 128
#define NT 128
#define BK 32

typedef __bf16 bf16x8 __attribute__((ext_vector_type(8)));
typedef float floatx4 __attribute__((ext_vector_type(4)));
typedef _Float16 halfx8 __attribute__((ext_vector_type(8)));

__device__ __forceinline__ unsigned short f2bf(float x) {
    union { __hip_bfloat16 b; unsigned short u; } cv;
    cv.b = __float2bfloat16(x);
    return cv.u;
}
__device__ __forceinline__ float bf2f(unsigned short u) {
    union { __hip_bfloat16 b; unsigned short u; } cv;
    cv.u = u;
    return __bfloat162float(cv.b);
}

__device__ __forceinline__ floatx4 mfma16(bf16x8 a, bf16x8 b, floatx4 c) {
    return __builtin_amdgcn_mfma_f32_16x16x32_bf16(a, b, c, 0, 0, 0);
}

// async global->LDS, 16B per lane. LDS dest = wave-uniform base + lane*16;
// we pass per-thread pointers whose first-lane value is the wave base.
__device__ __forceinline__ void ldg2lds16(const unsigned short* g, unsigned short* l) {
    __builtin_amdgcn_global_load_lds(
        (const __attribute__((address_space(1))) unsigned int*)g,
        (__attribute__((address_space(3))) unsigned int*)l, 16, 0, 0);
}

// ---------------- init scratch ----------------
__global__ void k_init(float* deg, int* cnt, int* fill, int* gstart, int* gend,
                       float* psum, unsigned int* pmax) {
    int i = blockIdx.x * blockDim.x + threadIdx.x;
    if (i < NN) { deg[i] = 1.0f; cnt[i] = 0; fill[i] = 0; }
    if (i < BB) { gstart[i] = NN; gend[i] = 0; }
    if (i < BB * DD) { psum[i] = 0.f; pmax[i] = 0u; }
}

// ---------------- weighted degree + in-degree counts ----------------
__global__ void k_deg(const int* __restrict__ ei, const int* __restrict__ sd,
                      float* __restrict__ deg, int* __restrict__ cnt) {
    int e = blockIdx.x * blockDim.x + threadIdx.x;
    if (e >= EE) return;
    int c = ei[EE + e];
    float w = (sd[e] == 1) ? 1.0f : 0.7f;
    atomicAdd(&deg[c], w);
    atomicAdd(&cnt[c], 1);
}

__global__ void k_dis(const float* __restrict__ deg, float* __restrict__ dis) {
    int i = blockIdx.x * blockDim.x + threadIdx.x;
    if (i < NN) dis[i] = rsqrtf(fmaxf(deg[i], EPSV));
}

// ---------------- exclusive scan of counts -> rowptr ----------------
__global__ void k_scan1(const int* __restrict__ cnt, int* __restrict__ rowptr,
                        int* __restrict__ bsum) {
    __shared__ int sh[256];
    const int t = threadIdx.x;
    const int i = blockIdx.x * 256 + t;
    int v = (i < NN) ? cnt[i] : 0;
    sh[t] = v;
    __syncthreads();
    for (int off = 1; off < 256; off <<= 1) {
        int y = (t >= off) ? sh[t - off] : 0;
        __syncthreads();
        if (t >= off) sh[t] += y;
        __syncthreads();
    }
    if (i < NN) rowptr[i] = sh[t] - v;   // exclusive
    if (t == 255) bsum[blockIdx.x] = sh[255];
}

__global__ void k_scan2(int* __restrict__ bsum, int* __restrict__ rowptr, int nb) {
    if (threadIdx.x == 0 && blockIdx.x == 0) {
        int run = 0;
        for (int b = 0; b < nb; b++) { int t = bsum[b]; bsum[b] = run; run += t; }
        rowptr[NN] = run;
    }
}

__global__ void k_scan3(int* __restrict__ rowptr, const int* __restrict__ bsum) {
    int i = blockIdx.x * blockDim.x + threadIdx.x;
    if (i < NN) rowptr[i] += bsum[i >> 8];
}

// ---------------- CSR fill: per-dest src list + edge norm ----------------
__global__ void k_fill(const int* __restrict__ ei, const int* __restrict__ sd,
                       const float* __restrict__ dis, const int* __restrict__ rowptr,
                       int* __restrict__ fill, int* __restrict__ srcs,
                       float* __restrict__ enorm) {
    int e = blockIdx.x * blockDim.x + threadIdx.x;
    if (e >= EE) return;
    int s = ei[e];
    int c = ei[EE + e];
    float w = (sd[e] == 1) ? 1.0f : 0.7f;
    int p = rowptr[c] + atomicAdd(&fill[c], 1);
    srcs[p] = s;
    enorm[p] = dis[s] * w * dis[c];
}

// ---------------- weights: fp32 -> transposed bf16 hi/lo ----------------
__global__ void k_wt(const float* __restrict__ Wc, unsigned short* __restrict__ WThi,
                     unsigned short* __restrict__ WTlo) {
    int i = blockIdx.x * blockDim.x + threadIdx.x;  // < LL*DD*DD
    int l = i >> 18;
    int rem = i & ((DD * DD) - 1);
    int n = rem >> 9;
    int k = rem & (DD - 1);
    float v = Wc[(l << 18) + (k << 9) + n];
    unsigned short hb = f2bf(v);
    WThi[i] = hb;
    WTlo[i] = f2bf(v - bf2f(hb));
}

// ---------------- fp32 -> bf16 hi/lo split (layer-0 input x) ----------------
__global__ void k_split(const float* __restrict__ src, unsigned short* __restrict__ hi,
                        unsigned short* __restrict__ lo, int n) {
    int i = blockIdx.x * blockDim.x + threadIdx.x;
    if (i >= n) return;
    float v = src[i];
    unsigned short hb = f2bf(v);
    hi[i] = hb;
    lo[i] = f2bf(v - bf2f(hb));
}

// ---------------- GEMM: C[N,D] = (Ahi+Alo) @ (Bhi+Blo), m97-style LDS staging ------
// 128x128 tile, BK=32, 4 waves each computing 64x64 (4x4 16x16x32 frags),
// 3-term hi/lo split: Ah*Bh + Ah*Bl + Al*Bh. Output fp16 (gather precision is enough).
__launch_bounds__(256)
__global__ void k_gemm(const unsigned short* __restrict__ Ahi,
                       const unsigned short* __restrict__ Alo,
                       const unsigned short* __restrict__ Bhi,
                       const unsigned short* __restrict__ Blo,
                       _Float16* __restrict__ C) {
    __shared__ unsigned short sAh[MT * BK];
    __shared__ unsigned short sAl[MT * BK];
    __shared__ unsigned short sBh[NT * BK];
    __shared__ unsigned short sBl[NT * BK];

    const int t = threadIdx.x;
    const int wid = t >> 6;
    const int lane = t & 63;
    const int l15 = lane & 15;
    const int quad = lane >> 4;
    const int m0 = blockIdx.y * MT;
    const int n0 = blockIdx.x * NT;
    const int wr = (wid >> 1) * 64;   // wave row offset in tile
    const int wc = (wid & 1) * 64;    // wave col offset in tile

    // staging addresses: thread t covers tile-linear elements [t*8, t*8+8)
    const int srow = t >> 2;
    const int skoff = (t & 3) * 8;
    const unsigned short* gAh = Ahi + (size_t)(m0 + srow) * DD + skoff;
    const unsigned short* gAl = Alo + (size_t)(m0 + srow) * DD + skoff;
    const unsigned short* gBh = Bhi + (size_t)(n0 + srow) * DD + skoff;
    const unsigned short* gBl = Blo + (size_t)(n0 + srow) * DD + skoff;
    unsigned short* lA = sAh + t * 8;   // first-lane value is wave base
    unsigned short* lAl = sAl + t * 8;
    unsigned short* lB = sBh + t * 8;
    unsigned short* lBl = sBl + t * 8;

    floatx4 acc[4][4];
#pragma unroll
    for (int i = 0; i < 4; i++)
#pragma unroll
        for (int j = 0; j < 4; j++) acc[i][j] = (floatx4){0.f, 0.f, 0.f, 0.f};

    for (int k0 = 0; k0 < DD; k0 += BK) {
        __syncthreads();   // previous compute done before overwriting LDS
        ldg2lds16(gAh + k0, lA);
        ldg2lds16(gAh + 64 * DD + k0, lA + 64 * BK);
        ldg2lds16(gAl + k0, lAl);
        ldg2lds16(gAl + 64 * DD + k0, lAl + 64 * BK);
        ldg2lds16(gBh + k0, lB);
        ldg2lds16(gBh + 64 * DD + k0, lB + 64 * BK);
        ldg2lds16(gBl + k0, lBl);
        ldg2lds16(gBl + 64 * DD + k0, lBl + 64 * BK);
        __syncthreads();   // compiler drains vmcnt before barrier

        bf16x8 ah[4], al[4], bh[4], bl[4];
#pragma unroll
        for (int i = 0; i < 4; i++) {
            const int ar = (wr + i * 16 + l15) * BK + quad * 8;
            const int br = (wc + i * 16 + l15) * BK + quad * 8;
            ah[i] = *(const bf16x8*)&sAh[ar];
            al[i] = *(const bf16x8*)&sAl[ar];
            bh[i] = *(const bf16x8*)&sBh[br];
            bl[i] = *(const bf16x8*)&sBl[br];
        }
#pragma unroll
        for (int i = 0; i < 4; i++)
#pragma unroll
            for (int j = 0; j < 4; j++) {
                acc[i][j] = mfma16(ah[i], bh[j], acc[i][j]);
                acc[i][j] = mfma16(ah[i], bl[j], acc[i][j]);
                acc[i][j] = mfma16(al[i], bh[j], acc[i][j]);
            }
    }

#pragma unroll
    for (int i = 0; i < 4; i++) {
        const int rbase = m0 + wr + i * 16 + quad * 4;
#pragma unroll
        for (int j = 0; j < 4; j++) {
            const int gcol = n0 + wc + j * 16 + l15;
#pragma unroll
            for (int r = 0; r < 4; r++) {
                const int grow = rbase + r;
                if (grow < NN) C[(size_t)grow * DD + gcol] = (_Float16)acc[i][j][r];
            }
        }
    }
}

// ---------------- aggregate + bias + BN + ReLU + bf16 hi/lo split ----------------
__device__ __forceinline__ void bn_pack_store(
    float v0, float v1, float v2, float v3, int cidx,
    const float4* __restrict__ bc4, const float4* __restrict__ g4,
    const float4* __restrict__ b4, const float4* __restrict__ rm4,
    const float4* __restrict__ rv4, uint2* __restrict__ oh, uint2* __restrict__ ol) {
    float4 bcv = bc4[cidx], gv = g4[cidx], bv = b4[cidx], rmv = rm4[cidx], rvv = rv4[cidx];
    float h0 = fmaxf(gv.x * (v0 + bcv.x - rmv.x) * rsqrtf(rvv.x + EPSV) + bv.x, 0.f);
    float h1 = fmaxf(gv.y * (v1 + bcv.y - rmv.y) * rsqrtf(rvv.y + EPSV) + bv.y, 0.f);
    float h2 = fmaxf(gv.z * (v2 + bcv.z - rmv.z) * rsqrtf(rvv.z + EPSV) + bv.z, 0.f);
    float h3 = fmaxf(gv.w * (v3 + bcv.w - rmv.w) * rsqrtf(rvv.w + EPSV) + bv.w, 0.f);
    unsigned short p0 = f2bf(h0), p1 = f2bf(h1), p2 = f2bf(h2), p3 = f2bf(h3);
    uint2 uh;
    uh.x = (unsigned)p0 | ((unsigned)p1 << 16);
    uh.y = (unsigned)p2 | ((unsigned)p3 << 16);
    unsigned short q0 = f2bf(h0 - bf2f(p0)), q1 = f2bf(h1 - bf2f(p1));
    unsigned short q2 = f2bf(h2 - bf2f(p2)), q3 = f2bf(h3 - bf2f(p3));
    uint2 ul;
    ul.x = (unsigned)q0 | ((unsigned)q1 << 16);
    ul.y = (unsigned)q2 | ((unsigned)q3 << 16);
    oh[cidx] = uh;
    ol[cidx] = ul;
}

// one wave per node; lane covers channels [lane*8, lane*8+8): one 16B fp16 load/row.
__launch_bounds__(64)
__global__ void k_agg(const _Float16* __restrict__ hw, const int* __restrict__ rowptr,
                      const int* __restrict__ srcs, const float* __restrict__ enorm,
                      const float* __restrict__ dis,
                      const float* __restrict__ bcl, const float* __restrict__ gl,
                      const float* __restrict__ bl_, const float* __restrict__ rml,
                      const float* __restrict__ rvl,
                      unsigned short* __restrict__ Hhi, unsigned short* __restrict__ Hlo) {
    const int n = blockIdx.x;
    const int lane = threadIdx.x;
    const float dn = dis[n];
    const float sw = dn * dn;  // self-loop norm
    const halfx8* rown = (const halfx8*)(hw + (size_t)n * DD);
    halfx8 a = rown[lane];
    float acc[8];
#pragma unroll
    for (int k = 0; k < 8; k++) acc[k] = (float)a[k] * sw;
    const int s0 = rowptr[n], s1 = rowptr[n + 1];
    int i = s0;
    // 4-edge unrolled: 4 independent 16B loads in flight per lane
    for (; i + 4 <= s1; i += 4) {
        const int sa = srcs[i], sb = srcs[i + 1], sc = srcs[i + 2], se = srcs[i + 3];
        const float wa = enorm[i], wb = enorm[i + 1], wc = enorm[i + 2], we = enorm[i + 3];
        halfx8 pa = ((const halfx8*)(hw + (size_t)sa * DD))[lane];
        halfx8 pb = ((const halfx8*)(hw + (size_t)sb * DD))[lane];
        halfx8 pc = ((const halfx8*)(hw + (size_t)sc * DD))[lane];
        halfx8 pe = ((const halfx8*)(hw + (size_t)se * DD))[lane];
#pragma unroll
        for (int k = 0; k < 8; k++) acc[k] = fmaf((float)pa[k], wa, acc[k]);
#pragma unroll
        for (int k = 0; k < 8; k++) acc[k] = fmaf((float)pb[k], wb, acc[k]);
#pragma unroll
        for (int k = 0; k < 8; k++) acc[k] = fmaf((float)pc[k], wc, acc[k]);
#pragma unroll
        for (int k = 0; k < 8; k++) acc[k] = fmaf((float)pe[k], we, acc[k]);
    }
    for (; i < s1; i++) {
        const int s = srcs[i];
        const float wn = enorm[i];
        halfx8 pb = ((const halfx8*)(hw + (size_t)s * DD))[lane];
#pragma unroll
        for (int k = 0; k < 8; k++) acc[k] = fmaf((float)pb[k], wn, acc[k]);
    }
    const float4* bc4 = (const float4*)bcl;
    const float4* g4 = (const float4*)gl;
    const float4* b4 = (const float4*)bl_;
    const float4* rm4 = (const float4*)rml;
    const float4* rv4 = (const float4*)rvl;
    uint2* oh = (uint2*)(Hhi + (size_t)n * DD);
    uint2* ol = (uint2*)(Hlo + (size_t)n * DD);
    bn_pack_store(acc[0], acc[1], acc[2], acc[3], lane * 2, bc4, g4, b4, rm4, rv4, oh, ol);
    bn_pack_store(acc[4], acc[5], acc[6], acc[7], lane * 2 + 1, bc4, g4, b4, rm4, rv4, oh, ol);
}

// ---------------- graph node ranges (batch sorted -> boundary detection, NO atomics) ----
__global__ void k_bounds(const int* __restrict__ batch, int* __restrict__ gstart,
                         int* __restrict__ gend) {
    int n = blockIdx.x * blockDim.x + threadIdx.x;
    if (n >= NN) return;
    int g = batch[n];
    int gp = (n == 0) ? -1 : batch[n - 1];
    if (g != gp) gstart[g] = n;          // first node of graph g
    int gn = (n == NN - 1) ? BB : batch[n + 1];
    if (g != gn) gend[g] = n + 1;        // one past last node of graph g
}

// ---------------- mean/max pooling (8 slices per graph) ----------------
__launch_bounds__(512)
__global__ void k_pool(const unsigned short* __restrict__ Hhi,
                       const unsigned short* __restrict__ Hlo,
                       const int* __restrict__ gstart, const int* __restrict__ gend,
                       float* __restrict__ psum, unsigned int* __restrict__ pmax) {
    const int g = blockIdx.x;
    const int sl = blockIdx.y;
    const int c = threadIdx.x;
    const int s0 = gstart[g], e0 = gend[g];
    if (e0 <= s0) return;
    const int len = e0 - s0;
    const int chunk = (len + 7) >> 3;
    const int lo = s0 + sl * chunk;
    const int hi = min(lo + chunk, e0);
    float sum = 0.f, mx = 0.f;
    for (int n = lo; n < hi; n++) {
        float v = bf2f(Hhi[(size_t)n * DD + c]) + bf2f(Hlo[(size_t)n * DD + c]);
        sum += v;
        mx = fmaxf(mx, v);
    }
    if (lo < hi) {
        atomicAdd(&psum[g * DD + c], sum);
        atomicMax(&pmax[g * DD + c], __float_as_uint(fmaxf(mx, 0.f)));  // h >= 0
    }
}

// ---------------- final linear + log_softmax ----------------
__global__ void k_final(const float* __restrict__ psum, const unsigned int* __restrict__ pmax,
                        const int* __restrict__ gstart, const int* __restrict__ gend,
                        const float* __restrict__ Wlin, const float* __restrict__ blin,
                        float* __restrict__ out) {
    __shared__ float zs[BB * OUTC];
    const int t = threadIdx.x;  // 0..127
    const int g = t >> 1, o = t & 1;
    int cntg = gend[g] - gstart[g];
    if (cntg < 0) cntg = 0;
    const float inv = 1.0f / (float)max(cntg, 1);
    float z = blin[o];
    for (int k = 0; k < DD; k++)
        z += psum[g * DD + k] * inv * Wlin[k * OUTC + o];
    for (int k = 0; k < DD; k++)
        z += __uint_as_float(pmax[g * DD + k]) * Wlin[(DD + k) * OUTC + o];
    zs[t] = z;
    __syncthreads();
    float zo = zs[t ^ 1];
    float m = fmaxf(z, zo);
    float ls = m + logf(expf(z - m) + expf(zo - m));
    out[t] = z - ls;
}

extern "C" void kernel_launch(void* const* d_in, const int* in_sizes, int n_in,
                              void* d_out, int out_size, void* d_ws, size_t ws_size,
                              hipStream_t stream) {
    const float* x = (const float*)d_in[0];
    const int* ei = (const int*)d_in[1];
    const int* batch = (const int*)d_in[2];
    const int* sd = (const int*)d_in[3];
    const float* Wc = (const float*)d_in[4];
    const float* bc = (const float*)d_in[5];
    const float* gamma = (const float*)d_in[6];
    const float* beta = (const float*)d_in[7];
    const float* rmean = (const float*)d_in[8];
    const float* rvar = (const float*)d_in[9];
    const float* Wlin = (const float*)d_in[10];
    const float* blin = (const float*)d_in[11];
    float* out = (float*)d_out;

    char* p = (char*)d_ws;
    auto alloc = [&](size_t bytes) {
        char* r = p;
        p += (bytes + 255) & ~(size_t)255;
        return r;
    };
    _Float16* hw = (_Float16*)alloc((size_t)NN * DD * 2);
    unsigned short* Hhi = (unsigned short*)alloc((size_t)NN * DD * 2);
    unsigned short* Hlo = (unsigned short*)alloc((size_t)NN * DD * 2);
    unsigned short* WThi = (unsigned short*)alloc((size_t)LL * DD * DD * 2);
    unsigned short* WTlo = (unsigned short*)alloc((size_t)LL * DD * DD * 2);
    float* deg = (float*)alloc(NN * 4);
    float* dis = (float*)alloc(NN * 4);
    int* cnt = (int*)alloc(NN * 4);
    int* fill = (int*)alloc(NN * 4);
    int* rowptr = (int*)alloc((NN + 1) * 4);
    int* bsum = (int*)alloc(256 * 4);
    int* srcs = (int*)alloc(EE * 4);
    float* enorm = (float*)alloc(EE * 4);
    int* gstart = (int*)alloc(BB * 4);
    int* gend = (int*)alloc(BB * 4);
    float* psum = (float*)alloc(BB * DD * 4);
    unsigned int* pmax = (unsigned int*)alloc(BB * DD * 4);
    (void)ws_size; (void)in_sizes; (void)n_in; (void)out_size;

    const int nb256 = (NN + 255) / 256;          // 196
    const int eb256 = (EE + 255) / 256;          // 3125

    k_init<<<nb256, 256, 0, stream>>>(deg, cnt, fill, gstart, gend, psum, pmax);
    k_deg<<<eb256, 256, 0, stream>>>(ei, sd, deg, cnt);
    k_dis<<<nb256, 256, 0, stream>>>(deg, dis);
    k_scan1<<<nb256, 256, 0, stream>>>(cnt, rowptr, bsum);
    k_scan2<<<1, 1, 0, stream>>>(bsum, rowptr, nb256);
    k_scan3<<<nb256, 256, 0, stream>>>(rowptr, bsum);
    k_fill<<<eb256, 256, 0, stream>>>(ei, sd, dis, rowptr, fill, srcs, enorm);
    k_wt<<<(LL * DD * DD) / 256, 256, 0, stream>>>(Wc, WThi, WTlo);
    k_split<<<(NN * DD + 255) / 256, 256, 0, stream>>>(x, Hhi, Hlo, NN * DD);

    // n-tile fastest so co-resident blocks share A slabs in L2/L3
    dim3 ggrid(DD / NT, (NN + MT - 1) / MT);  // (4, 391)
    for (int l = 0; l < LL; l++) {
        k_gemm<<<ggrid, 256, 0, stream>>>(Hhi, Hlo, WThi + (size_t)l * DD * DD,
                                          WTlo + (size_t)l * DD * DD, hw);
        k_agg<<<NN, 64, 0, stream>>>(hw, rowptr, srcs, enorm, dis,
                                     bc + l * DD, gamma + l * DD, beta + l * DD,
                                     rmean + l * DD, rvar + l * DD, Hhi, Hlo);
    }

    k_bounds<<<nb256, 256, 0, stream>>>(batch, gstart, gend);
    k_pool<<<dim3(BB, 8), 512, 0, stream>>>(Hhi, Hlo, gstart, gend, psum, pmax);
    k_final<<<1, BB * OUTC, 0, stream>>>(psum, pmax, gstart, gend, Wlin, blin, out);
}

// Round 5
// 1100.925 us; speedup vs baseline: 3.1689x; 1.2231x over previous
//
#include <hip/hip_runtime.h>
#include <hip/hip_bf16.h>

#define NN 50000
#define EE 800000
#define DD 512
#define BB 64
#define LL 4
#define OUTC 2
#define EPSV 1e-5f

#define MT 128
#define NT 128
#define BK 32

typedef _Float16 halfx8 __attribute__((ext_vector_type(8)));
typedef float floatx4 __attribute__((ext_vector_type(4)));

__device__ __forceinline__ floatx4 mfma16h(halfx8 a, halfx8 b, floatx4 c) {
    return __builtin_amdgcn_mfma_f32_16x16x32_f16(a, b, c, 0, 0, 0);
}

// async global->LDS, 16B per lane. LDS dest = wave-uniform base + lane*16.
__device__ __forceinline__ void ldg2lds16(const _Float16* g, _Float16* l) {
    __builtin_amdgcn_global_load_lds(
        (const __attribute__((address_space(1))) unsigned int*)g,
        (__attribute__((address_space(3))) unsigned int*)l, 16, 0, 0);
}

// ---------------- init scratch ----------------
__global__ void k_init(float* deg, int* cnt, int* fill, int* gstart, int* gend,
                       float* psum, unsigned int* pmax) {
    int i = blockIdx.x * blockDim.x + threadIdx.x;
    if (i < NN) { deg[i] = 1.0f; cnt[i] = 0; fill[i] = 0; }
    if (i < BB) { gstart[i] = NN; gend[i] = 0; }
    if (i < BB * DD) { psum[i] = 0.f; pmax[i] = 0u; }
}

// ---------------- weighted degree + in-degree counts ----------------
__global__ void k_deg(const int* __restrict__ ei, const int* __restrict__ sd,
                      float* __restrict__ deg, int* __restrict__ cnt) {
    int e = blockIdx.x * blockDim.x + threadIdx.x;
    if (e >= EE) return;
    int c = ei[EE + e];
    float w = (sd[e] == 1) ? 1.0f : 0.7f;
    atomicAdd(&deg[c], w);
    atomicAdd(&cnt[c], 1);
}

__global__ void k_dis(const float* __restrict__ deg, float* __restrict__ dis) {
    int i = blockIdx.x * blockDim.x + threadIdx.x;
    if (i < NN) dis[i] = rsqrtf(fmaxf(deg[i], EPSV));
}

// ---------------- exclusive scan of counts -> rowptr ----------------
__global__ void k_scan1(const int* __restrict__ cnt, int* __restrict__ rowptr,
                        int* __restrict__ bsum) {
    __shared__ int sh[256];
    const int t = threadIdx.x;
    const int i = blockIdx.x * 256 + t;
    int v = (i < NN) ? cnt[i] : 0;
    sh[t] = v;
    __syncthreads();
    for (int off = 1; off < 256; off <<= 1) {
        int y = (t >= off) ? sh[t - off] : 0;
        __syncthreads();
        if (t >= off) sh[t] += y;
        __syncthreads();
    }
    if (i < NN) rowptr[i] = sh[t] - v;   // exclusive
    if (t == 255) bsum[blockIdx.x] = sh[255];
}

__global__ void k_scan2(int* __restrict__ bsum, int* __restrict__ rowptr, int nb) {
    if (threadIdx.x == 0 && blockIdx.x == 0) {
        int run = 0;
        for (int b = 0; b < nb; b++) { int t = bsum[b]; bsum[b] = run; run += t; }
        rowptr[NN] = run;
    }
}

__global__ void k_scan3(int* __restrict__ rowptr, const int* __restrict__ bsum) {
    int i = blockIdx.x * blockDim.x + threadIdx.x;
    if (i < NN) rowptr[i] += bsum[i >> 8];
}

// ---------------- CSR fill: per-dest src list + edge norm ----------------
__global__ void k_fill(const int* __restrict__ ei, const int* __restrict__ sd,
                       const float* __restrict__ dis, const int* __restrict__ rowptr,
                       int* __restrict__ fill, int* __restrict__ srcs,
                       float* __restrict__ enorm) {
    int e = blockIdx.x * blockDim.x + threadIdx.x;
    if (e >= EE) return;
    int s = ei[e];
    int c = ei[EE + e];
    float w = (sd[e] == 1) ? 1.0f : 0.7f;
    int p = rowptr[c] + atomicAdd(&fill[c], 1);
    srcs[p] = s;
    enorm[p] = dis[s] * w * dis[c];
}

// ---------------- weights: fp32 -> transposed fp16 ----------------
__global__ void k_wt(const float* __restrict__ Wc, _Float16* __restrict__ WT) {
    int i = blockIdx.x * blockDim.x + threadIdx.x;  // < LL*DD*DD
    int l = i >> 18;
    int rem = i & ((DD * DD) - 1);
    int n = rem >> 9;
    int k = rem & (DD - 1);
    WT[i] = (_Float16)Wc[(l << 18) + (k << 9) + n];
}

// ---------------- fp32 -> fp16 (layer-0 input x) ----------------
__global__ void k_split(const float* __restrict__ src, _Float16* __restrict__ dst, int n) {
    int i = blockIdx.x * blockDim.x + threadIdx.x;
    if (i < n) dst[i] = (_Float16)src[i];
}

// ---------------- GEMM: C[N,D] = H @ WT^T, fp16 MFMA, m97-style LDS staging ------
// 128x128 tile, BK=32, 4 waves each computing 64x64 (4x4 16x16x32 frags).
__launch_bounds__(256)
__global__ void k_gemm(const _Float16* __restrict__ A,
                       const _Float16* __restrict__ B,   // [n][k] transposed
                       _Float16* __restrict__ C) {
    __shared__ _Float16 sA[MT * BK];
    __shared__ _Float16 sB[NT * BK];

    const int t = threadIdx.x;
    const int wid = t >> 6;
    const int lane = t & 63;
    const int l15 = lane & 15;
    const int quad = lane >> 4;
    const int m0 = blockIdx.y * MT;
    const int n0 = blockIdx.x * NT;
    const int wr = (wid >> 1) * 64;   // wave row offset in tile
    const int wc = (wid & 1) * 64;    // wave col offset in tile

    // staging: thread t covers tile-linear elements [t*8, t*8+8)
    // = row t/4, k-offset (t%4)*8 of a [rows x BK] fp16 tile.
    const int srow = t >> 2;
    const int skoff = (t & 3) * 8;
    const _Float16* gA = A + (size_t)(m0 + srow) * DD + skoff;
    const _Float16* gB = B + (size_t)(n0 + srow) * DD + skoff;
    _Float16* lA = sA + t * 8;   // first-lane value is wave base
    _Float16* lB = sB + t * 8;

    floatx4 acc[4][4];
#pragma unroll
    for (int i = 0; i < 4; i++)
#pragma unroll
        for (int j = 0; j < 4; j++) acc[i][j] = (floatx4){0.f, 0.f, 0.f, 0.f};

    for (int k0 = 0; k0 < DD; k0 += BK) {
        __syncthreads();   // previous compute done before overwriting LDS
        ldg2lds16(gA + k0, lA);
        ldg2lds16(gA + 64 * DD + k0, lA + 64 * BK);
        ldg2lds16(gB + k0, lB);
        ldg2lds16(gB + 64 * DD + k0, lB + 64 * BK);
        __syncthreads();   // compiler drains vmcnt before barrier

        halfx8 a[4], b[4];
#pragma unroll
        for (int i = 0; i < 4; i++) {
            a[i] = *(const halfx8*)&sA[(wr + i * 16 + l15) * BK + quad * 8];
            b[i] = *(const halfx8*)&sB[(wc + i * 16 + l15) * BK + quad * 8];
        }
#pragma unroll
        for (int i = 0; i < 4; i++)
#pragma unroll
            for (int j = 0; j < 4; j++)
                acc[i][j] = mfma16h(a[i], b[j], acc[i][j]);
    }

#pragma unroll
    for (int i = 0; i < 4; i++) {
        const int rbase = m0 + wr + i * 16 + quad * 4;
#pragma unroll
        for (int j = 0; j < 4; j++) {
            const int gcol = n0 + wc + j * 16 + l15;
#pragma unroll
            for (int r = 0; r < 4; r++) {
                const int grow = rbase + r;
                if (grow < NN) C[(size_t)grow * DD + gcol] = (_Float16)acc[i][j][r];
            }
        }
    }
}

// ---------------- aggregate + bias + BN + ReLU -> fp16 H ----------------
// one wave per node; lane covers channels [lane*8, lane*8+8): one 16B load/row.
__launch_bounds__(64)
__global__ void k_agg(const _Float16* __restrict__ hw, const int* __restrict__ rowptr,
                      const int* __restrict__ srcs, const float* __restrict__ enorm,
                      const float* __restrict__ dis,
                      const float* __restrict__ bcl, const float* __restrict__ gl,
                      const float* __restrict__ bl_, const float* __restrict__ rml,
                      const float* __restrict__ rvl,
                      _Float16* __restrict__ H) {
    const int n = blockIdx.x;
    const int lane = threadIdx.x;
    const float dn = dis[n];
    const float sw = dn * dn;  // self-loop norm
    halfx8 a = ((const halfx8*)(hw + (size_t)n * DD))[lane];
    float acc[8];
#pragma unroll
    for (int k = 0; k < 8; k++) acc[k] = (float)a[k] * sw;
    const int s0 = rowptr[n], s1 = rowptr[n + 1];
    int i = s0;
    // 4-edge unrolled: 4 independent 16B loads in flight per lane
    for (; i + 4 <= s1; i += 4) {
        const int sa = srcs[i], sb = srcs[i + 1], sc = srcs[i + 2], se = srcs[i + 3];
        const float wa = enorm[i], wb = enorm[i + 1], wc = enorm[i + 2], we = enorm[i + 3];
        halfx8 pa = ((const halfx8*)(hw + (size_t)sa * DD))[lane];
        halfx8 pb = ((const halfx8*)(hw + (size_t)sb * DD))[lane];
        halfx8 pc = ((const halfx8*)(hw + (size_t)sc * DD))[lane];
        halfx8 pe = ((const halfx8*)(hw + (size_t)se * DD))[lane];
#pragma unroll
        for (int k = 0; k < 8; k++) acc[k] = fmaf((float)pa[k], wa, acc[k]);
#pragma unroll
        for (int k = 0; k < 8; k++) acc[k] = fmaf((float)pb[k], wb, acc[k]);
#pragma unroll
        for (int k = 0; k < 8; k++) acc[k] = fmaf((float)pc[k], wc, acc[k]);
#pragma unroll
        for (int k = 0; k < 8; k++) acc[k] = fmaf((float)pe[k], we, acc[k]);
    }
    for (; i < s1; i++) {
        const int s = srcs[i];
        const float wn = enorm[i];
        halfx8 pb = ((const halfx8*)(hw + (size_t)s * DD))[lane];
#pragma unroll
        for (int k = 0; k < 8; k++) acc[k] = fmaf((float)pb[k], wn, acc[k]);
    }
    // BN + ReLU epilogue, channels lane*8 .. lane*8+7
    const float4* bc4 = (const float4*)bcl;
    const float4* g4 = (const float4*)gl;
    const float4* b4 = (const float4*)bl_;
    const float4* rm4 = (const float4*)rml;
    const float4* rv4 = (const float4*)rvl;
    halfx8 hv;
#pragma unroll
    for (int half4 = 0; half4 < 2; half4++) {
        const int cidx = lane * 2 + half4;
        float4 bcv = bc4[cidx], gv = g4[cidx], bv = b4[cidx], rmv = rm4[cidx], rvv = rv4[cidx];
        float h0 = fmaxf(gv.x * (acc[half4 * 4 + 0] + bcv.x - rmv.x) * rsqrtf(rvv.x + EPSV) + bv.x, 0.f);
        float h1 = fmaxf(gv.y * (acc[half4 * 4 + 1] + bcv.y - rmv.y) * rsqrtf(rvv.y + EPSV) + bv.y, 0.f);
        float h2 = fmaxf(gv.z * (acc[half4 * 4 + 2] + bcv.z - rmv.z) * rsqrtf(rvv.z + EPSV) + bv.z, 0.f);
        float h3 = fmaxf(gv.w * (acc[half4 * 4 + 3] + bcv.w - rmv.w) * rsqrtf(rvv.w + EPSV) + bv.w, 0.f);
        hv[half4 * 4 + 0] = (_Float16)h0;
        hv[half4 * 4 + 1] = (_Float16)h1;
        hv[half4 * 4 + 2] = (_Float16)h2;
        hv[half4 * 4 + 3] = (_Float16)h3;
    }
    ((halfx8*)(H + (size_t)n * DD))[lane] = hv;
}

// ---------------- graph node ranges (batch sorted -> boundary detection, NO atomics) ----
__global__ void k_bounds(const int* __restrict__ batch, int* __restrict__ gstart,
                         int* __restrict__ gend) {
    int n = blockIdx.x * blockDim.x + threadIdx.x;
    if (n >= NN) return;
    int g = batch[n];
    int gp = (n == 0) ? -1 : batch[n - 1];
    if (g != gp) gstart[g] = n;          // first node of graph g
    int gn = (n == NN - 1) ? BB : batch[n + 1];
    if (g != gn) gend[g] = n + 1;        // one past last node of graph g
}

// ---------------- mean/max pooling (8 slices per graph) ----------------
__launch_bounds__(512)
__global__ void k_pool(const _Float16* __restrict__ H,
                       const int* __restrict__ gstart, const int* __restrict__ gend,
                       float* __restrict__ psum, unsigned int* __restrict__ pmax) {
    const int g = blockIdx.x;
    const int sl = blockIdx.y;
    const int c = threadIdx.x;
    const int s0 = gstart[g], e0 = gend[g];
    if (e0 <= s0) return;
    const int len = e0 - s0;
    const int chunk = (len + 7) >> 3;
    const int lo = s0 + sl * chunk;
    const int hi = min(lo + chunk, e0);
    float sum = 0.f, mx = 0.f;
    for (int n = lo; n < hi; n++) {
        float v = (float)H[(size_t)n * DD + c];
        sum += v;
        mx = fmaxf(mx, v);
    }
    if (lo < hi) {
        atomicAdd(&psum[g * DD + c], sum);
        atomicMax(&pmax[g * DD + c], __float_as_uint(fmaxf(mx, 0.f)));  // h >= 0
    }
}

// ---------------- final linear + log_softmax ----------------
__global__ void k_final(const float* __restrict__ psum, const unsigned int* __restrict__ pmax,
                        const int* __restrict__ gstart, const int* __restrict__ gend,
                        const float* __restrict__ Wlin, const float* __restrict__ blin,
                        float* __restrict__ out) {
    __shared__ float zs[BB * OUTC];
    const int t = threadIdx.x;  // 0..127
    const int g = t >> 1, o = t & 1;
    int cntg = gend[g] - gstart[g];
    if (cntg < 0) cntg = 0;
    const float inv = 1.0f / (float)max(cntg, 1);
    float z = blin[o];
    for (int k = 0; k < DD; k++)
        z += psum[g * DD + k] * inv * Wlin[k * OUTC + o];
    for (int k = 0; k < DD; k++)
        z += __uint_as_float(pmax[g * DD + k]) * Wlin[(DD + k) * OUTC + o];
    zs[t] = z;
    __syncthreads();
    float zo = zs[t ^ 1];
    float m = fmaxf(z, zo);
    float ls = m + logf(expf(z - m) + expf(zo - m));
    out[t] = z - ls;
}

extern "C" void kernel_launch(void* const* d_in, const int* in_sizes, int n_in,
                              void* d_out, int out_size, void* d_ws, size_t ws_size,
                              hipStream_t stream) {
    const float* x = (const float*)d_in[0];
    const int* ei = (const int*)d_in[1];
    const int* batch = (const int*)d_in[2];
    const int* sd = (const int*)d_in[3];
    const float* Wc = (const float*)d_in[4];
    const float* bc = (const float*)d_in[5];
    const float* gamma = (const float*)d_in[6];
    const float* beta = (const float*)d_in[7];
    const float* rmean = (const float*)d_in[8];
    const float* rvar = (const float*)d_in[9];
    const float* Wlin = (const float*)d_in[10];
    const float* blin = (const float*)d_in[11];
    float* out = (float*)d_out;

    char* p = (char*)d_ws;
    auto alloc = [&](size_t bytes) {
        char* r = p;
        p += (bytes + 255) & ~(size_t)255;
        return r;
    };
    _Float16* hw = (_Float16*)alloc((size_t)NN * DD * 2);
    _Float16* H = (_Float16*)alloc((size_t)NN * DD * 2);
    _Float16* WT = (_Float16*)alloc((size_t)LL * DD * DD * 2);
    float* deg = (float*)alloc(NN * 4);
    float* dis = (float*)alloc(NN * 4);
    int* cnt = (int*)alloc(NN * 4);
    int* fill = (int*)alloc(NN * 4);
    int* rowptr = (int*)alloc((NN + 1) * 4);
    int* bsum = (int*)alloc(256 * 4);
    int* srcs = (int*)alloc(EE * 4);
    float* enorm = (float*)alloc(EE * 4);
    int* gstart = (int*)alloc(BB * 4);
    int* gend = (int*)alloc(BB * 4);
    float* psum = (float*)alloc(BB * DD * 4);
    unsigned int* pmax = (unsigned int*)alloc(BB * DD * 4);
    (void)ws_size; (void)in_sizes; (void)n_in; (void)out_size;

    const int nb256 = (NN + 255) / 256;          // 196
    const int eb256 = (EE + 255) / 256;          // 3125

    k_init<<<nb256, 256, 0, stream>>>(deg, cnt, fill, gstart, gend, psum, pmax);
    k_deg<<<eb256, 256, 0, stream>>>(ei, sd, deg, cnt);
    k_dis<<<nb256, 256, 0, stream>>>(deg, dis);
    k_scan1<<<nb256, 256, 0, stream>>>(cnt, rowptr, bsum);
    k_scan2<<<1, 1, 0, stream>>>(bsum, rowptr, nb256);
    k_scan3<<<nb256, 256, 0, stream>>>(rowptr, bsum);
    k_fill<<<eb256, 256, 0, stream>>>(ei, sd, dis, rowptr, fill, srcs, enorm);
    k_wt<<<(LL * DD * DD) / 256, 256, 0, stream>>>(Wc, WT);
    k_split<<<(NN * DD + 255) / 256, 256, 0, stream>>>(x, H, NN * DD);

    // n-tile fastest so co-resident blocks share A slabs in L2/L3
    dim3 ggrid(DD / NT, (NN + MT - 1) / MT);  // (4, 391)
    for (int l = 0; l < LL; l++) {
        k_gemm<<<ggrid, 256, 0, stream>>>(H, WT + (size_t)l * DD * DD, hw);
        k_agg<<<NN, 64, 0, stream>>>(hw, rowptr, srcs, enorm, dis,
                                     bc + l * DD, gamma + l * DD, beta + l * DD,
                                     rmean + l * DD, rvar + l * DD, H);
    }

    k_bounds<<<nb256, 256, 0, stream>>>(batch, gstart, gend);
    k_pool<<<dim3(BB, 8), 512, 0, stream>>>(H, gstart, gend, psum, pmax);
    k_final<<<1, BB * OUTC, 0, stream>>>(psum, pmax, gstart, gend, Wlin, blin, out);
}

// Round 6
// 1060.705 us; speedup vs baseline: 3.2891x; 1.0379x over previous
//
#include <hip/hip_runtime.h>
#include <hip/hip_bf16.h>

#define NN 50000
#define EE 800000
#define DD 512
#define BB 64
#define LL 4
#define OUTC 2
#define EPSV 1e-5f

#define MT 128
#define NT 128
#define BK 32

typedef _Float16 halfx8 __attribute__((ext_vector_type(8)));
typedef float floatx4 __attribute__((ext_vector_type(4)));

__device__ __forceinline__ floatx4 mfma16h(halfx8 a, halfx8 b, floatx4 c) {
    return __builtin_amdgcn_mfma_f32_16x16x32_f16(a, b, c, 0, 0, 0);
}

// async global->LDS, 16B per lane. LDS dest = wave-uniform base + lane*16.
__device__ __forceinline__ void ldg2lds16(const _Float16* g, _Float16* l) {
    __builtin_amdgcn_global_load_lds(
        (const __attribute__((address_space(1))) unsigned int*)g,
        (__attribute__((address_space(3))) unsigned int*)l, 16, 0, 0);
}

// ---------------- fused prep: init scratch + W transpose->fp16 + x->fp16 ----------
// disjoint index regions, one launch, overlapping memory traffic
__global__ void k_prep(const float* __restrict__ x, const float* __restrict__ Wc,
                       _Float16* __restrict__ H, _Float16* __restrict__ WT,
                       float* __restrict__ deg, int* __restrict__ cnt,
                       int* __restrict__ fill, int* __restrict__ gstart,
                       int* __restrict__ gend, float* __restrict__ psum,
                       unsigned int* __restrict__ pmax) {
    int i = blockIdx.x * blockDim.x + threadIdx.x;
    if (i < NN * DD) H[i] = (_Float16)x[i];
    if (i < LL * DD * DD) {
        int l = i >> 18;
        int rem = i & ((DD * DD) - 1);
        int n = rem >> 9;
        int k = rem & (DD - 1);
        WT[i] = (_Float16)Wc[(l << 18) + (k << 9) + n];
    }
    if (i < NN) { deg[i] = 1.0f; cnt[i] = 0; fill[i] = 0; }
    if (i < BB) { gstart[i] = NN; gend[i] = 0; }
    if (i < BB * DD) { psum[i] = 0.f; pmax[i] = 0u; }
}

// ---------------- weighted degree + in-degree counts ----------------
__global__ void k_deg(const int* __restrict__ ei, const int* __restrict__ sd,
                      float* __restrict__ deg, int* __restrict__ cnt) {
    int e = blockIdx.x * blockDim.x + threadIdx.x;
    if (e >= EE) return;
    int c = ei[EE + e];
    float w = (sd[e] == 1) ? 1.0f : 0.7f;
    atomicAdd(&deg[c], w);
    atomicAdd(&cnt[c], 1);
}

// ---------------- scan block 1 (+ fused dis + fused graph bounds) ----------------
__global__ void k_scan1(const int* __restrict__ cnt, int* __restrict__ rowptr,
                        int* __restrict__ bsum, const float* __restrict__ deg,
                        float* __restrict__ dis, const int* __restrict__ batch,
                        int* __restrict__ gstart, int* __restrict__ gend) {
    __shared__ int sh[256];
    const int t = threadIdx.x;
    const int i = blockIdx.x * 256 + t;
    if (i < NN) {
        dis[i] = rsqrtf(fmaxf(deg[i], EPSV));
        // batch is sorted: boundary detection, no atomics
        int g = batch[i];
        int gp = (i == 0) ? -1 : batch[i - 1];
        if (g != gp) gstart[g] = i;
        int gn = (i == NN - 1) ? BB : batch[i + 1];
        if (g != gn) gend[g] = i + 1;
    }
    int v = (i < NN) ? cnt[i] : 0;
    sh[t] = v;
    __syncthreads();
    for (int off = 1; off < 256; off <<= 1) {
        int y = (t >= off) ? sh[t - off] : 0;
        __syncthreads();
        if (t >= off) sh[t] += y;
        __syncthreads();
    }
    if (i < NN) rowptr[i] = sh[t] - v;   // exclusive
    if (t == 255) bsum[blockIdx.x] = sh[255];
}

__global__ void k_scan2(int* __restrict__ bsum, int* __restrict__ rowptr, int nb) {
    if (threadIdx.x == 0 && blockIdx.x == 0) {
        int run = 0;
        for (int b = 0; b < nb; b++) { int t = bsum[b]; bsum[b] = run; run += t; }
        rowptr[NN] = run;
    }
}

__global__ void k_scan3(int* __restrict__ rowptr, const int* __restrict__ bsum) {
    int i = blockIdx.x * blockDim.x + threadIdx.x;
    if (i < NN) rowptr[i] += bsum[i >> 8];
}

// ---------------- CSR fill: per-dest src list + edge norm ----------------
__global__ void k_fill(const int* __restrict__ ei, const int* __restrict__ sd,
                       const float* __restrict__ dis, const int* __restrict__ rowptr,
                       int* __restrict__ fill, int* __restrict__ srcs,
                       float* __restrict__ enorm) {
    int e = blockIdx.x * blockDim.x + threadIdx.x;
    if (e >= EE) return;
    int s = ei[e];
    int c = ei[EE + e];
    float w = (sd[e] == 1) ? 1.0f : 0.7f;
    int p = rowptr[c] + atomicAdd(&fill[c], 1);
    srcs[p] = s;
    enorm[p] = dis[s] * w * dis[c];
}

// ---------------- GEMM: C[N,D] = H @ WT^T, fp16 MFMA, m97-style LDS staging ------
// 128x128 tile, BK=32, 4 waves each computing 64x64 (4x4 16x16x32 frags).
__launch_bounds__(256)
__global__ void k_gemm(const _Float16* __restrict__ A,
                       const _Float16* __restrict__ B,   // [n][k] transposed
                       _Float16* __restrict__ C) {
    __shared__ _Float16 sA[MT * BK];
    __shared__ _Float16 sB[NT * BK];

    const int t = threadIdx.x;
    const int wid = t >> 6;
    const int lane = t & 63;
    const int l15 = lane & 15;
    const int quad = lane >> 4;
    const int m0 = blockIdx.y * MT;
    const int n0 = blockIdx.x * NT;
    const int wr = (wid >> 1) * 64;   // wave row offset in tile
    const int wc = (wid & 1) * 64;    // wave col offset in tile

    // staging: thread t covers tile-linear elements [t*8, t*8+8)
    const int srow = t >> 2;
    const int skoff = (t & 3) * 8;
    const _Float16* gA = A + (size_t)(m0 + srow) * DD + skoff;
    const _Float16* gB = B + (size_t)(n0 + srow) * DD + skoff;
    _Float16* lA = sA + t * 8;   // first-lane value is wave base
    _Float16* lB = sB + t * 8;

    floatx4 acc[4][4];
#pragma unroll
    for (int i = 0; i < 4; i++)
#pragma unroll
        for (int j = 0; j < 4; j++) acc[i][j] = (floatx4){0.f, 0.f, 0.f, 0.f};

    for (int k0 = 0; k0 < DD; k0 += BK) {
        __syncthreads();   // previous compute done before overwriting LDS
        ldg2lds16(gA + k0, lA);
        ldg2lds16(gA + 64 * DD + k0, lA + 64 * BK);
        ldg2lds16(gB + k0, lB);
        ldg2lds16(gB + 64 * DD + k0, lB + 64 * BK);
        __syncthreads();   // compiler drains vmcnt before barrier

        halfx8 a[4], b[4];
#pragma unroll
        for (int i = 0; i < 4; i++) {
            a[i] = *(const halfx8*)&sA[(wr + i * 16 + l15) * BK + quad * 8];
            b[i] = *(const halfx8*)&sB[(wc + i * 16 + l15) * BK + quad * 8];
        }
#pragma unroll
        for (int i = 0; i < 4; i++)
#pragma unroll
            for (int j = 0; j < 4; j++)
                acc[i][j] = mfma16h(a[i], b[j], acc[i][j]);
    }

#pragma unroll
    for (int i = 0; i < 4; i++) {
        const int rbase = m0 + wr + i * 16 + quad * 4;
#pragma unroll
        for (int j = 0; j < 4; j++) {
            const int gcol = n0 + wc + j * 16 + l15;
#pragma unroll
            for (int r = 0; r < 4; r++) {
                const int grow = rbase + r;
                if (grow < NN) C[(size_t)grow * DD + gcol] = (_Float16)acc[i][j][r];
            }
        }
    }
}

// ---------------- aggregate + bias + BN + ReLU -> fp16 H ----------------
// one wave per node; lane covers channels [lane*8, lane*8+8): one 16B load/row.
// 8-edge unroll: 8 independent 16B gathers in flight per lane.
__launch_bounds__(64)
__global__ void k_agg(const _Float16* __restrict__ hw, const int* __restrict__ rowptr,
                      const int* __restrict__ srcs, const float* __restrict__ enorm,
                      const float* __restrict__ dis,
                      const float* __restrict__ bcl, const float* __restrict__ gl,
                      const float* __restrict__ bl_, const float* __restrict__ rml,
                      const float* __restrict__ rvl,
                      _Float16* __restrict__ H) {
    const int n = blockIdx.x;
    const int lane = threadIdx.x;
    const float dn = dis[n];
    const float sw = dn * dn;  // self-loop norm
    halfx8 a = ((const halfx8*)(hw + (size_t)n * DD))[lane];
    float acc[8];
#pragma unroll
    for (int k = 0; k < 8; k++) acc[k] = (float)a[k] * sw;
    const int s0 = rowptr[n], s1 = rowptr[n + 1];
    int i = s0;
    for (; i + 8 <= s1; i += 8) {
        int sv[8];
        float wv[8];
        halfx8 pv[8];
#pragma unroll
        for (int u = 0; u < 8; u++) { sv[u] = srcs[i + u]; wv[u] = enorm[i + u]; }
#pragma unroll
        for (int u = 0; u < 8; u++)
            pv[u] = ((const halfx8*)(hw + (size_t)sv[u] * DD))[lane];
#pragma unroll
        for (int u = 0; u < 8; u++)
#pragma unroll
            for (int k = 0; k < 8; k++) acc[k] = fmaf((float)pv[u][k], wv[u], acc[k]);
    }
    for (; i + 4 <= s1; i += 4) {
        int sv[4];
        float wv[4];
        halfx8 pv[4];
#pragma unroll
        for (int u = 0; u < 4; u++) { sv[u] = srcs[i + u]; wv[u] = enorm[i + u]; }
#pragma unroll
        for (int u = 0; u < 4; u++)
            pv[u] = ((const halfx8*)(hw + (size_t)sv[u] * DD))[lane];
#pragma unroll
        for (int u = 0; u < 4; u++)
#pragma unroll
            for (int k = 0; k < 8; k++) acc[k] = fmaf((float)pv[u][k], wv[u], acc[k]);
    }
    for (; i < s1; i++) {
        const int s = srcs[i];
        const float wn = enorm[i];
        halfx8 pb = ((const halfx8*)(hw + (size_t)s * DD))[lane];
#pragma unroll
        for (int k = 0; k < 8; k++) acc[k] = fmaf((float)pb[k], wn, acc[k]);
    }
    // BN + ReLU epilogue, channels lane*8 .. lane*8+7
    const float4* bc4 = (const float4*)bcl;
    const float4* g4 = (const float4*)gl;
    const float4* b4 = (const float4*)bl_;
    const float4* rm4 = (const float4*)rml;
    const float4* rv4 = (const float4*)rvl;
    halfx8 hv;
#pragma unroll
    for (int half4 = 0; half4 < 2; half4++) {
        const int cidx = lane * 2 + half4;
        float4 bcv = bc4[cidx], gv = g4[cidx], bv = b4[cidx], rmv = rm4[cidx], rvv = rv4[cidx];
        float h0 = fmaxf(gv.x * (acc[half4 * 4 + 0] + bcv.x - rmv.x) * rsqrtf(rvv.x + EPSV) + bv.x, 0.f);
        float h1 = fmaxf(gv.y * (acc[half4 * 4 + 1] + bcv.y - rmv.y) * rsqrtf(rvv.y + EPSV) + bv.y, 0.f);
        float h2 = fmaxf(gv.z * (acc[half4 * 4 + 2] + bcv.z - rmv.z) * rsqrtf(rvv.z + EPSV) + bv.z, 0.f);
        float h3 = fmaxf(gv.w * (acc[half4 * 4 + 3] + bcv.w - rmv.w) * rsqrtf(rvv.w + EPSV) + bv.w, 0.f);
        hv[half4 * 4 + 0] = (_Float16)h0;
        hv[half4 * 4 + 1] = (_Float16)h1;
        hv[half4 * 4 + 2] = (_Float16)h2;
        hv[half4 * 4 + 3] = (_Float16)h3;
    }
    ((halfx8*)(H + (size_t)n * DD))[lane] = hv;
}

// ---------------- mean/max pooling (8 slices per graph) ----------------
__launch_bounds__(512)
__global__ void k_pool(const _Float16* __restrict__ H,
                       const int* __restrict__ gstart, const int* __restrict__ gend,
                       float* __restrict__ psum, unsigned int* __restrict__ pmax) {
    const int g = blockIdx.x;
    const int sl = blockIdx.y;
    const int c = threadIdx.x;
    const int s0 = gstart[g], e0 = gend[g];
    if (e0 <= s0) return;
    const int len = e0 - s0;
    const int chunk = (len + 7) >> 3;
    const int lo = s0 + sl * chunk;
    const int hi = min(lo + chunk, e0);
    float sum = 0.f, mx = 0.f;
    for (int n = lo; n < hi; n++) {
        float v = (float)H[(size_t)n * DD + c];
        sum += v;
        mx = fmaxf(mx, v);
    }
    if (lo < hi) {
        atomicAdd(&psum[g * DD + c], sum);
        atomicMax(&pmax[g * DD + c], __float_as_uint(fmaxf(mx, 0.f)));  // h >= 0
    }
}

// ---------------- final linear + log_softmax: one wave per graph ----------------
__launch_bounds__(64)
__global__ void k_final(const float* __restrict__ psum, const unsigned int* __restrict__ pmax,
                        const int* __restrict__ gstart, const int* __restrict__ gend,
                        const float* __restrict__ Wlin, const float* __restrict__ blin,
                        float* __restrict__ out) {
    const int g = blockIdx.x;
    const int lane = threadIdx.x;
    int cntg = gend[g] - gstart[g];
    if (cntg < 1) cntg = 1;   // empty graph: psum/pmax are 0, value of inv irrelevant
    const float inv = 1.0f / (float)cntg;
    float z0 = 0.f, z1 = 0.f;
#pragma unroll
    for (int j = 0; j < 8; j++) {
        const int k = j * 64 + lane;
        float mean = psum[g * DD + k] * inv;
        float mx = __uint_as_float(pmax[g * DD + k]);
        z0 += mean * Wlin[k * OUTC + 0] + mx * Wlin[(DD + k) * OUTC + 0];
        z1 += mean * Wlin[k * OUTC + 1] + mx * Wlin[(DD + k) * OUTC + 1];
    }
#pragma unroll
    for (int off = 32; off > 0; off >>= 1) {
        z0 += __shfl_down(z0, off);
        z1 += __shfl_down(z1, off);
    }
    if (lane == 0) {
        z0 += blin[0];
        z1 += blin[1];
        float m = fmaxf(z0, z1);
        float ls = m + logf(expf(z0 - m) + expf(z1 - m));
        out[g * OUTC + 0] = z0 - ls;
        out[g * OUTC + 1] = z1 - ls;
    }
}

extern "C" void kernel_launch(void* const* d_in, const int* in_sizes, int n_in,
                              void* d_out, int out_size, void* d_ws, size_t ws_size,
                              hipStream_t stream) {
    const float* x = (const float*)d_in[0];
    const int* ei = (const int*)d_in[1];
    const int* batch = (const int*)d_in[2];
    const int* sd = (const int*)d_in[3];
    const float* Wc = (const float*)d_in[4];
    const float* bc = (const float*)d_in[5];
    const float* gamma = (const float*)d_in[6];
    const float* beta = (const float*)d_in[7];
    const float* rmean = (const float*)d_in[8];
    const float* rvar = (const float*)d_in[9];
    const float* Wlin = (const float*)d_in[10];
    const float* blin = (const float*)d_in[11];
    float* out = (float*)d_out;

    char* p = (char*)d_ws;
    auto alloc = [&](size_t bytes) {
        char* r = p;
        p += (bytes + 255) & ~(size_t)255;
        return r;
    };
    _Float16* hw = (_Float16*)alloc((size_t)NN * DD * 2);
    _Float16* H = (_Float16*)alloc((size_t)NN * DD * 2);
    _Float16* WT = (_Float16*)alloc((size_t)LL * DD * DD * 2);
    float* deg = (float*)alloc(NN * 4);
    float* dis = (float*)alloc(NN * 4);
    int* cnt = (int*)alloc(NN * 4);
    int* fill = (int*)alloc(NN * 4);
    int* rowptr = (int*)alloc((NN + 1) * 4);
    int* bsum = (int*)alloc(256 * 4);
    int* srcs = (int*)alloc(EE * 4);
    float* enorm = (float*)alloc(EE * 4);
    int* gstart = (int*)alloc(BB * 4);
    int* gend = (int*)alloc(BB * 4);
    float* psum = (float*)alloc(BB * DD * 4);
    unsigned int* pmax = (unsigned int*)alloc(BB * DD * 4);
    (void)ws_size; (void)in_sizes; (void)n_in; (void)out_size;

    const int nb256 = (NN + 255) / 256;          // 196
    const int eb256 = (EE + 255) / 256;          // 3125

    k_prep<<<(NN * DD + 255) / 256, 256, 0, stream>>>(x, Wc, H, WT, deg, cnt, fill,
                                                      gstart, gend, psum, pmax);
    k_deg<<<eb256, 256, 0, stream>>>(ei, sd, deg, cnt);
    k_scan1<<<nb256, 256, 0, stream>>>(cnt, rowptr, bsum, deg, dis, batch, gstart, gend);
    k_scan2<<<1, 1, 0, stream>>>(bsum, rowptr, nb256);
    k_scan3<<<nb256, 256, 0, stream>>>(rowptr, bsum);
    k_fill<<<eb256, 256, 0, stream>>>(ei, sd, dis, rowptr, fill, srcs, enorm);

    // n-tile fastest so co-resident blocks share A slabs in L2/L3
    dim3 ggrid(DD / NT, (NN + MT - 1) / MT);  // (4, 391)
    for (int l = 0; l < LL; l++) {
        k_gemm<<<ggrid, 256, 0, stream>>>(H, WT + (size_t)l * DD * DD, hw);
        k_agg<<<NN, 64, 0, stream>>>(hw, rowptr, srcs, enorm, dis,
                                     bc + l * DD, gamma + l * DD, beta + l * DD,
                                     rmean + l * DD, rvar + l * DD, H);
    }

    k_pool<<<dim3(BB, 8), 512, 0, stream>>>(H, gstart, gend, psum, pmax);
    k_final<<<BB, 64, 0, stream>>>(psum, pmax, gstart, gend, Wlin, blin, out);
}

// Round 7
// 1043.962 us; speedup vs baseline: 3.3418x; 1.0160x over previous
//
#include <hip/hip_runtime.h>
#include <hip/hip_bf16.h>

#define NN 50000
#define EE 800000
#define DD 512
#define BB 64
#define LL 4
#define OUTC 2
#define EPSV 1e-5f

#define MT 128
#define NT 128
#define BK 32

typedef _Float16 halfx8 __attribute__((ext_vector_type(8)));
typedef float floatx4 __attribute__((ext_vector_type(4)));

__device__ __forceinline__ floatx4 mfma16h(halfx8 a, halfx8 b, floatx4 c) {
    return __builtin_amdgcn_mfma_f32_16x16x32_f16(a, b, c, 0, 0, 0);
}

// async global->LDS, 16B per lane. LDS dest = wave-uniform base + lane*16.
__device__ __forceinline__ void ldg2lds16(const _Float16* g, _Float16* l) {
    __builtin_amdgcn_global_load_lds(
        (const __attribute__((address_space(1))) unsigned int*)g,
        (__attribute__((address_space(3))) unsigned int*)l, 16, 0, 0);
}

// ---------------- fused prep: init scratch + W transpose->fp16 + x->fp16 ----------
__global__ void k_prep(const float* __restrict__ x, const float* __restrict__ Wc,
                       _Float16* __restrict__ H, _Float16* __restrict__ WT,
                       float* __restrict__ deg, int* __restrict__ cnt,
                       int* __restrict__ fill, int* __restrict__ gstart,
                       int* __restrict__ gend, float* __restrict__ psum,
                       unsigned int* __restrict__ pmax) {
    int i = blockIdx.x * blockDim.x + threadIdx.x;
    if (i < NN * DD) H[i] = (_Float16)x[i];
    if (i < LL * DD * DD) {
        int l = i >> 18;
        int rem = i & ((DD * DD) - 1);
        int n = rem >> 9;
        int k = rem & (DD - 1);
        WT[i] = (_Float16)Wc[(l << 18) + (k << 9) + n];
    }
    if (i < NN) { deg[i] = 1.0f; cnt[i] = 0; fill[i] = 0; }
    if (i < BB) { gstart[i] = NN; gend[i] = 0; }
    if (i < BB * DD) { psum[i] = 0.f; pmax[i] = 0u; }
}

// ---------------- weighted degree + in-degree counts ----------------
__global__ void k_deg(const int* __restrict__ ei, const int* __restrict__ sd,
                      float* __restrict__ deg, int* __restrict__ cnt) {
    int e = blockIdx.x * blockDim.x + threadIdx.x;
    if (e >= EE) return;
    int c = ei[EE + e];
    float w = (sd[e] == 1) ? 1.0f : 0.7f;
    atomicAdd(&deg[c], w);
    atomicAdd(&cnt[c], 1);
}

// ---------------- scan block 1 (+ fused dis + fused graph bounds) ----------------
__global__ void k_scan1(const int* __restrict__ cnt, int* __restrict__ rowptr,
                        int* __restrict__ bsum, const float* __restrict__ deg,
                        float* __restrict__ dis, const int* __restrict__ batch,
                        int* __restrict__ gstart, int* __restrict__ gend) {
    __shared__ int sh[256];
    const int t = threadIdx.x;
    const int i = blockIdx.x * 256 + t;
    if (i < NN) {
        dis[i] = rsqrtf(fmaxf(deg[i], EPSV));
        // batch is sorted: boundary detection, no atomics
        int g = batch[i];
        int gp = (i == 0) ? -1 : batch[i - 1];
        if (g != gp) gstart[g] = i;
        int gn = (i == NN - 1) ? BB : batch[i + 1];
        if (g != gn) gend[g] = i + 1;
    }
    int v = (i < NN) ? cnt[i] : 0;
    sh[t] = v;
    __syncthreads();
    for (int off = 1; off < 256; off <<= 1) {
        int y = (t >= off) ? sh[t - off] : 0;
        __syncthreads();
        if (t >= off) sh[t] += y;
        __syncthreads();
    }
    if (i < NN) rowptr[i] = sh[t] - v;   // exclusive
    if (t == 255) bsum[blockIdx.x] = sh[255];
}

__global__ void k_scan2(int* __restrict__ bsum, int* __restrict__ rowptr, int nb) {
    if (threadIdx.x == 0 && blockIdx.x == 0) {
        int run = 0;
        for (int b = 0; b < nb; b++) { int t = bsum[b]; bsum[b] = run; run += t; }
        rowptr[NN] = run;
    }
}

__global__ void k_scan3(int* __restrict__ rowptr, const int* __restrict__ bsum) {
    int i = blockIdx.x * blockDim.x + threadIdx.x;
    if (i < NN) rowptr[i] += bsum[i >> 8];
}

// ---------------- CSR fill: per-dest src list + edge norm ----------------
__global__ void k_fill(const int* __restrict__ ei, const int* __restrict__ sd,
                       const float* __restrict__ dis, const int* __restrict__ rowptr,
                       int* __restrict__ fill, int* __restrict__ srcs,
                       float* __restrict__ enorm) {
    int e = blockIdx.x * blockDim.x + threadIdx.x;
    if (e >= EE) return;
    int s = ei[e];
    int c = ei[EE + e];
    float w = (sd[e] == 1) ? 1.0f : 0.7f;
    int p = rowptr[c] + atomicAdd(&fill[c], 1);
    srcs[p] = s;
    enorm[p] = dis[s] * w * dis[c];
}

// ---------------- GEMM: C[N,D] = H @ WT^T, fp16 MFMA, m97-style LDS staging ------
__launch_bounds__(256)
__global__ void k_gemm(const _Float16* __restrict__ A,
                       const _Float16* __restrict__ B,   // [n][k] transposed
                       _Float16* __restrict__ C) {
    __shared__ _Float16 sA[MT * BK];
    __shared__ _Float16 sB[NT * BK];

    const int t = threadIdx.x;
    const int wid = t >> 6;
    const int lane = t & 63;
    const int l15 = lane & 15;
    const int quad = lane >> 4;
    const int m0 = blockIdx.y * MT;
    const int n0 = blockIdx.x * NT;
    const int wr = (wid >> 1) * 64;   // wave row offset in tile
    const int wc = (wid & 1) * 64;    // wave col offset in tile

    const int srow = t >> 2;
    const int skoff = (t & 3) * 8;
    const _Float16* gA = A + (size_t)(m0 + srow) * DD + skoff;
    const _Float16* gB = B + (size_t)(n0 + srow) * DD + skoff;
    _Float16* lA = sA + t * 8;   // first-lane value is wave base
    _Float16* lB = sB + t * 8;

    floatx4 acc[4][4];
#pragma unroll
    for (int i = 0; i < 4; i++)
#pragma unroll
        for (int j = 0; j < 4; j++) acc[i][j] = (floatx4){0.f, 0.f, 0.f, 0.f};

    for (int k0 = 0; k0 < DD; k0 += BK) {
        __syncthreads();   // previous compute done before overwriting LDS
        ldg2lds16(gA + k0, lA);
        ldg2lds16(gA + 64 * DD + k0, lA + 64 * BK);
        ldg2lds16(gB + k0, lB);
        ldg2lds16(gB + 64 * DD + k0, lB + 64 * BK);
        __syncthreads();   // compiler drains vmcnt before barrier

        halfx8 a[4], b[4];
#pragma unroll
        for (int i = 0; i < 4; i++) {
            a[i] = *(const halfx8*)&sA[(wr + i * 16 + l15) * BK + quad * 8];
            b[i] = *(const halfx8*)&sB[(wc + i * 16 + l15) * BK + quad * 8];
        }
#pragma unroll
        for (int i = 0; i < 4; i++)
#pragma unroll
            for (int j = 0; j < 4; j++)
                acc[i][j] = mfma16h(a[i], b[j], acc[i][j]);
    }

#pragma unroll
    for (int i = 0; i < 4; i++) {
        const int rbase = m0 + wr + i * 16 + quad * 4;
#pragma unroll
        for (int j = 0; j < 4; j++) {
            const int gcol = n0 + wc + j * 16 + l15;
#pragma unroll
            for (int r = 0; r < 4; r++) {
                const int grow = rbase + r;
                if (grow < NN) C[(size_t)grow * DD + gcol] = (_Float16)acc[i][j][r];
            }
        }
    }
}

// ---------------- aggregate + bias + BN + ReLU -> fp16 H ----------------
// 4 nodes per 256-thread block (1 wave per node, no barriers): block-slot limit
// stops binding -> ~32 waves/CU for latency hiding. lane covers channels
// [lane*8, lane*8+8): one 16B load per gathered row.
__launch_bounds__(256)
__global__ void k_agg(const _Float16* __restrict__ hw, const int* __restrict__ rowptr,
                      const int* __restrict__ srcs, const float* __restrict__ enorm,
                      const float* __restrict__ dis,
                      const float* __restrict__ bcl, const float* __restrict__ gl,
                      const float* __restrict__ bl_, const float* __restrict__ rml,
                      const float* __restrict__ rvl,
                      _Float16* __restrict__ H) {
    const int n = blockIdx.x * 4 + (threadIdx.x >> 6);
    const int lane = threadIdx.x & 63;
    if (n >= NN) return;
    const float dn = dis[n];
    const float sw = dn * dn;  // self-loop norm
    halfx8 a = ((const halfx8*)(hw + (size_t)n * DD))[lane];
    float acc[8];
#pragma unroll
    for (int k = 0; k < 8; k++) acc[k] = (float)a[k] * sw;
    const int s0 = rowptr[n], s1 = rowptr[n + 1];
    int i = s0;
    for (; i + 8 <= s1; i += 8) {
        int sv[8];
        float wv[8];
        halfx8 pv[8];
#pragma unroll
        for (int u = 0; u < 8; u++) { sv[u] = srcs[i + u]; wv[u] = enorm[i + u]; }
#pragma unroll
        for (int u = 0; u < 8; u++)
            pv[u] = ((const halfx8*)(hw + (size_t)sv[u] * DD))[lane];
#pragma unroll
        for (int u = 0; u < 8; u++)
#pragma unroll
            for (int k = 0; k < 8; k++) acc[k] = fmaf((float)pv[u][k], wv[u], acc[k]);
    }
    for (; i + 4 <= s1; i += 4) {
        int sv[4];
        float wv[4];
        halfx8 pv[4];
#pragma unroll
        for (int u = 0; u < 4; u++) { sv[u] = srcs[i + u]; wv[u] = enorm[i + u]; }
#pragma unroll
        for (int u = 0; u < 4; u++)
            pv[u] = ((const halfx8*)(hw + (size_t)sv[u] * DD))[lane];
#pragma unroll
        for (int u = 0; u < 4; u++)
#pragma unroll
            for (int k = 0; k < 8; k++) acc[k] = fmaf((float)pv[u][k], wv[u], acc[k]);
    }
    for (; i < s1; i++) {
        const int s = srcs[i];
        const float wn = enorm[i];
        halfx8 pb = ((const halfx8*)(hw + (size_t)s * DD))[lane];
#pragma unroll
        for (int k = 0; k < 8; k++) acc[k] = fmaf((float)pb[k], wn, acc[k]);
    }
    // BN + ReLU epilogue, channels lane*8 .. lane*8+7
    const float4* bc4 = (const float4*)bcl;
    const float4* g4 = (const float4*)gl;
    const float4* b4 = (const float4*)bl_;
    const float4* rm4 = (const float4*)rml;
    const float4* rv4 = (const float4*)rvl;
    halfx8 hv;
#pragma unroll
    for (int half4 = 0; half4 < 2; half4++) {
        const int cidx = lane * 2 + half4;
        float4 bcv = bc4[cidx], gv = g4[cidx], bv = b4[cidx], rmv = rm4[cidx], rvv = rv4[cidx];
        float h0 = fmaxf(gv.x * (acc[half4 * 4 + 0] + bcv.x - rmv.x) * rsqrtf(rvv.x + EPSV) + bv.x, 0.f);
        float h1 = fmaxf(gv.y * (acc[half4 * 4 + 1] + bcv.y - rmv.y) * rsqrtf(rvv.y + EPSV) + bv.y, 0.f);
        float h2 = fmaxf(gv.z * (acc[half4 * 4 + 2] + bcv.z - rmv.z) * rsqrtf(rvv.z + EPSV) + bv.z, 0.f);
        float h3 = fmaxf(gv.w * (acc[half4 * 4 + 3] + bcv.w - rmv.w) * rsqrtf(rvv.w + EPSV) + bv.w, 0.f);
        hv[half4 * 4 + 0] = (_Float16)h0;
        hv[half4 * 4 + 1] = (_Float16)h1;
        hv[half4 * 4 + 2] = (_Float16)h2;
        hv[half4 * 4 + 3] = (_Float16)h3;
    }
    ((halfx8*)(H + (size_t)n * DD))[lane] = hv;
}

// ---------------- mean/max pooling (8 slices per graph) ----------------
__launch_bounds__(512)
__global__ void k_pool(const _Float16* __restrict__ H,
                       const int* __restrict__ gstart, const int* __restrict__ gend,
                       float* __restrict__ psum, unsigned int* __restrict__ pmax) {
    const int g = blockIdx.x;
    const int sl = blockIdx.y;
    const int c = threadIdx.x;
    const int s0 = gstart[g], e0 = gend[g];
    if (e0 <= s0) return;
    const int len = e0 - s0;
    const int chunk = (len + 7) >> 3;
    const int lo = s0 + sl * chunk;
    const int hi = min(lo + chunk, e0);
    float sum = 0.f, mx = 0.f;
    for (int n = lo; n < hi; n++) {
        float v = (float)H[(size_t)n * DD + c];
        sum += v;
        mx = fmaxf(mx, v);
    }
    if (lo < hi) {
        atomicAdd(&psum[g * DD + c], sum);
        atomicMax(&pmax[g * DD + c], __float_as_uint(fmaxf(mx, 0.f)));  // h >= 0
    }
}

// ---------------- final linear + log_softmax: one wave per graph ----------------
__launch_bounds__(64)
__global__ void k_final(const float* __restrict__ psum, const unsigned int* __restrict__ pmax,
                        const int* __restrict__ gstart, const int* __restrict__ gend,
                        const float* __restrict__ Wlin, const float* __restrict__ blin,
                        float* __restrict__ out) {
    const int g = blockIdx.x;
    const int lane = threadIdx.x;
    int cntg = gend[g] - gstart[g];
    if (cntg < 1) cntg = 1;   // empty graph: psum/pmax are 0, value of inv irrelevant
    const float inv = 1.0f / (float)cntg;
    float z0 = 0.f, z1 = 0.f;
#pragma unroll
    for (int j = 0; j < 8; j++) {
        const int k = j * 64 + lane;
        float mean = psum[g * DD + k] * inv;
        float mx = __uint_as_float(pmax[g * DD + k]);
        z0 += mean * Wlin[k * OUTC + 0] + mx * Wlin[(DD + k) * OUTC + 0];
        z1 += mean * Wlin[k * OUTC + 1] + mx * Wlin[(DD + k) * OUTC + 1];
    }
#pragma unroll
    for (int off = 32; off > 0; off >>= 1) {
        z0 += __shfl_down(z0, off);
        z1 += __shfl_down(z1, off);
    }
    if (lane == 0) {
        z0 += blin[0];
        z1 += blin[1];
        float m = fmaxf(z0, z1);
        float ls = m + logf(expf(z0 - m) + expf(z1 - m));
        out[g * OUTC + 0] = z0 - ls;
        out[g * OUTC + 1] = z1 - ls;
    }
}

extern "C" void kernel_launch(void* const* d_in, const int* in_sizes, int n_in,
                              void* d_out, int out_size, void* d_ws, size_t ws_size,
                              hipStream_t stream) {
    const float* x = (const float*)d_in[0];
    const int* ei = (const int*)d_in[1];
    const int* batch = (const int*)d_in[2];
    const int* sd = (const int*)d_in[3];
    const float* Wc = (const float*)d_in[4];
    const float* bc = (const float*)d_in[5];
    const float* gamma = (const float*)d_in[6];
    const float* beta = (const float*)d_in[7];
    const float* rmean = (const float*)d_in[8];
    const float* rvar = (const float*)d_in[9];
    const float* Wlin = (const float*)d_in[10];
    const float* blin = (const float*)d_in[11];
    float* out = (float*)d_out;

    char* p = (char*)d_ws;
    auto alloc = [&](size_t bytes) {
        char* r = p;
        p += (bytes + 255) & ~(size_t)255;
        return r;
    };
    _Float16* hw = (_Float16*)alloc((size_t)NN * DD * 2);
    _Float16* H = (_Float16*)alloc((size_t)NN * DD * 2);
    _Float16* WT = (_Float16*)alloc((size_t)LL * DD * DD * 2);
    float* deg = (float*)alloc(NN * 4);
    float* dis = (float*)alloc(NN * 4);
    int* cnt = (int*)alloc(NN * 4);
    int* fill = (int*)alloc(NN * 4);
    int* rowptr = (int*)alloc((NN + 1) * 4);
    int* bsum = (int*)alloc(256 * 4);
    int* srcs = (int*)alloc(EE * 4);
    float* enorm = (float*)alloc(EE * 4);
    int* gstart = (int*)alloc(BB * 4);
    int* gend = (int*)alloc(BB * 4);
    float* psum = (float*)alloc(BB * DD * 4);
    unsigned int* pmax = (unsigned int*)alloc(BB * DD * 4);
    (void)ws_size; (void)in_sizes; (void)n_in; (void)out_size;

    const int nb256 = (NN + 255) / 256;          // 196
    const int eb256 = (EE + 255) / 256;          // 3125

    k_prep<<<(NN * DD + 255) / 256, 256, 0, stream>>>(x, Wc, H, WT, deg, cnt, fill,
                                                      gstart, gend, psum, pmax);
    k_deg<<<eb256, 256, 0, stream>>>(ei, sd, deg, cnt);
    k_scan1<<<nb256, 256, 0, stream>>>(cnt, rowptr, bsum, deg, dis, batch, gstart, gend);
    k_scan2<<<1, 1, 0, stream>>>(bsum, rowptr, nb256);
    k_scan3<<<nb256, 256, 0, stream>>>(rowptr, bsum);
    k_fill<<<eb256, 256, 0, stream>>>(ei, sd, dis, rowptr, fill, srcs, enorm);

    // n-tile fastest so co-resident blocks share A slabs in L2/L3
    dim3 ggrid(DD / NT, (NN + MT - 1) / MT);  // (4, 391)
    for (int l = 0; l < LL; l++) {
        k_gemm<<<ggrid, 256, 0, stream>>>(H, WT + (size_t)l * DD * DD, hw);
        k_agg<<<(NN + 3) / 4, 256, 0, stream>>>(hw, rowptr, srcs, enorm, dis,
                                                bc + l * DD, gamma + l * DD, beta + l * DD,
                                                rmean + l * DD, rvar + l * DD, H);
    }

    k_pool<<<dim3(BB, 8), 512, 0, stream>>>(H, gstart, gend, psum, pmax);
    k_final<<<BB, 64, 0, stream>>>(psum, pmax, gstart, gend, Wlin, blin, out);
}